// Round 19
// baseline (545.118 us; speedup 1.0000x reference)
//
#include <hip/hip_runtime.h>
#include <hip/hip_bf16.h>

#define E_EDGES 1000000
#define N_NODES 100000

typedef __attribute__((ext_vector_type(8))) short bf16x8;
typedef __attribute__((ext_vector_type(4))) float f32x4;

#define WAITV(N) asm volatile("s_waitcnt vmcnt(" #N ")" ::: "memory")
#define WAITL()  asm volatile("s_waitcnt lgkmcnt(0)" ::: "memory")
#define BAR()    __builtin_amdgcn_s_barrier()
#define PRIO1()  __builtin_amdgcn_s_setprio(1)
#define PRIO0()  __builtin_amdgcn_s_setprio(0)

__device__ __forceinline__ short f2bf(float f) {
    union { __bf16 b; short s; } u;
    u.b = (__bf16)f;
    return u.s;
}
__device__ __forceinline__ bf16x8 pack8(float4 a, float4 b) {
    bf16x8 r;
    r[0]=f2bf(a.x); r[1]=f2bf(a.y); r[2]=f2bf(a.z); r[3]=f2bf(a.w);
    r[4]=f2bf(b.x); r[5]=f2bf(b.y); r[6]=f2bf(b.z); r[7]=f2bf(b.w);
    return r;
}
__device__ __forceinline__ float4 ld4(const float* p) {
    return *reinterpret_cast<const float4*>(p);
}
__device__ __forceinline__ float silu1(float x) { return x / (1.f + __expf(-x)); }
__device__ __forceinline__ float tanh1(float x) {
    float e = __expf(2.f * x);
    return 1.f - 2.f / (e + 1.f);
}
__device__ __forceinline__ float bf2f(unsigned short u) {
    return __uint_as_float(((unsigned)u) << 16);
}

__device__ __forceinline__ void stage_frag(const short* gsrc, short* ldst) {
    __builtin_amdgcn_global_load_lds(
        (const __attribute__((address_space(1))) void*)gsrc,
        (__attribute__((address_space(3))) void*)ldst, 16, 0, 0);
}

// swizzled transpose index (shorts) within a per-wave 16x64 slice
__device__ __forceinline__ int tswz(int row, int colS) {
    return (row * 64 + colS) ^ ((row & 7) << 3);
}

// ============ FACTORED PATH ====================================================
// pack layout: frags 0-31 X (Win rows 256..383, ks*8+nt), 32-95 W_time,
// 96-127 W1, 128-131 W2, 132-195 hpre weights.
// Hpre is stored GATHER-ORDERED: position of col c (within each 128-half) is
// (c&15)*8 + (c>>4), so an edge lane reads its 8 needed values as ONE 16B load.
__global__ void pack_weights_f(const float* __restrict__ Wt,
                               const float* __restrict__ Win,
                               const float* __restrict__ W1,
                               const float* __restrict__ W2,
                               short* __restrict__ ws)
{
    int gid = blockIdx.x * 256 + threadIdx.x;
    if (gid >= 196 * 512) return;
    int frag = gid >> 9, within = gid & 511;
    int l = within >> 3, j = within & 7;
    int lg = l >> 4, ln = l & 15;
    int krow = (lg << 3) + j;
    float v;
    if (frag < 32) {                         // X: Win rows 256..383
        int ks = frag >> 3, nt = frag & 7;
        v = Win[(256 + ks * 32 + krow) * 128 + nt * 16 + ln];
    } else if (frag < 96) {                  // W_time
        int t = frag - 32, ch = t >> 3, sub = t & 7;
        int jj = sub >> 2, ks = sub & 3;
        int jcol = (ch < 4) ? (8 + 2 * ch + jj) : (2 * (ch - 4) + jj);
        v = Wt[(ks * 32 + krow) * 256 + jcol * 16 + ln];
    } else if (frag < 128) {                 // W1
        int t = frag - 96, ch = t >> 3, sub = t & 7;
        int nt = 2 * ch + (sub >> 2), ks = sub & 3;
        v = W1[(ks * 32 + krow) * 128 + nt * 16 + ln];
    } else if (frag < 132) {                 // W2 padded
        int ks = frag - 128;
        v = (ln < 4) ? W2[(ks * 32 + krow) * 4 + ln] : 0.0f;
    } else {                                 // hpre weights: Win rows 0..255
        int q = frag - 132;
        int ntc = q >> 2, ks = q & 3;
        int base = (ntc < 8) ? 0 : 128;
        v = Win[(base + ks * 32 + krow) * 128 + (ntc & 7) * 16 + ln];
    }
    ws[gid] = f2bf(v);
}

// Hpre[n] = h[n] @ Win[0:256], stored gather-ordered (see above).
__global__ __launch_bounds__(256)
void hpre_kernel(const float* __restrict__ h, const short* __restrict__ ws,
                 short* __restrict__ hp)
{
    const int tid = threadIdx.x;
    const int w   = tid >> 6;
    const int l   = tid & 63;
    const int ln  = l & 15;
    const int lg  = l >> 4;
    const int kb  = lg << 3;
    const int nb  = blockIdx.x * 64 + w * 16;
    const int nm  = min(nb + ln, N_NODES - 1);

    bf16x8 af[4];
    #pragma unroll
    for (int ks = 0; ks < 4; ++ks)
        af[ks] = pack8(ld4(h + (long)nm * 128 + ks*32 + kb),
                       ld4(h + (long)nm * 128 + ks*32 + kb + 4));
    const short* wsp = ws + 132 * 512;
    #pragma unroll
    for (int ntc = 0; ntc < 16; ++ntc) {
        f32x4 acc = (f32x4){0.f,0.f,0.f,0.f};
        #pragma unroll
        for (int ks = 0; ks < 4; ++ks) {
            bf16x8 b = *reinterpret_cast<const bf16x8*>(&wsp[(ntc*4+ks)*512 + l*8]);
            acc = __builtin_amdgcn_mfma_f32_16x16x32_bf16(af[ks], b, acc, 0, 0, 0);
        }
        // gather-ordered store: col c = ntc*16 + ln -> half*128 + ln*8 + (ntc&7)
        const int off = ((ntc < 8) ? 0 : 128) + ln * 8 + (ntc & 7);
        #pragma unroll
        for (int r = 0; r < 4; ++r) {
            int node = nb + (lg<<2) + r;
            if (node < N_NODES)
                hp[(long)node * 256 + off] = f2bf(acc[r]);
        }
    }
}

// factored edge kernel: 8 BIG phases (16 KB chunks, depth-2 dbuf) + W2.
// R19: deferred gather-add (hides Hpre latency under phases 0-1) + setprio.
__global__ __launch_bounds__(256, 3)
void edge_kernel_f(const float* __restrict__ pos,
                   const float* __restrict__ ea,
                   const float* __restrict__ dst_f,
                   const float* __restrict__ temb,
                   const float* __restrict__ adj,
                   const float* __restrict__ btime,
                   const float* __restrict__ bin,
                   const float* __restrict__ b1,
                   const float* __restrict__ cscale,
                   const int*   __restrict__ ei,
                   const short* __restrict__ ws,
                   const unsigned short* __restrict__ hp,
                   float* __restrict__ out)
{
    __shared__ __align__(16) short Wb[2][8192];   // 2 x 16 KB big-chunk dbuf
    __shared__ float sBias[512];

    const int tid = threadIdx.x;
    const int w   = tid >> 6;
    const int l   = tid & 63;
    const int ln  = l & 15;
    const int lg  = l >> 4;
    const int kb  = lg << 3;
    const int e0w = blockIdx.x * 64 + w * 16;
    const int em  = e0w + ln;

    const int ir = ei[em];
    const int ic = ei[E_EDGES + em];

    #pragma unroll
    for (int i = 0; i < 2; ++i) {
        int idx = tid + i * 256;
        float v = (idx < 128) ? bin[idx] : (idx < 256) ? b1[idx - 128] : btime[idx - 256];
        sBias[idx] = v;
    }
    WAITL();

    // big chunk C (16 frags): wave w stages frags 4w..4w+3 (its own 4 KB slice)
    #define STAGE16(C) { \
        const short* g_ = ws + (C) * 8192 + (w*4) * 512 + l * 8; \
        short* d_ = &Wb[(C) & 1][(w*4) * 512]; \
        stage_frag(g_, d_); \
        stage_frag(g_ + 512, d_ + 512); \
        stage_frag(g_ + 1024, d_ + 1024); \
        stage_frag(g_ + 1536, d_ + 1536); }
    #define STAGEW2() { \
        stage_frag(ws + 128 * 512 + w * 512 + l * 8, &Wb[0][w * 512]); }

    // C-layout row -> edge indices via shfl
    int irg[4], icg[4];
    #pragma unroll
    for (int r = 0; r < 4; ++r) {
        irg[r] = __shfl(ir, (lg<<2) + r);
        icg[r] = __shfl(ic, (lg<<2) + r);
    }

    // ---- prologue: tf loads -> C0,C1 stages -> Hpre gathers (newest) ----
    float4 tf[8];
    #pragma unroll
    for (int k2 = 0; k2 < 4; ++k2) {
        const float* q = (k2 < 2) ? (ea    + (long)em*64 + k2*32 + kb)
                                  : (dst_f + (long)em*64 + (k2-2)*32 + kb);
        tf[2*k2]   = ld4(q);
        tf[2*k2+1] = ld4(q + 4);
    }
    STAGE16(0);
    STAGE16(1);
    bf16x8 gaV[4], gbV[4];                    // gather-ordered: one 16B load each
    #pragma unroll
    for (int r = 0; r < 4; ++r) {
        gaV[r] = *reinterpret_cast<const bf16x8*>(hp + (long)irg[r]*256 + ln*8);
        gbV[r] = *reinterpret_cast<const bf16x8*>(hp + (long)icg[r]*256 + 128 + ln*8);
    }
    WAITV(16);                                // tf done; C0,C1,gathers in flight
    bf16x8 af_a[4];
    #pragma unroll
    for (int k2 = 0; k2 < 4; ++k2) af_a[k2] = pack8(tf[2*k2], tf[2*k2+1]);

    f32x4 accX[8];                            // start at ZERO; gathers folded later
    #pragma unroll
    for (int i = 0; i < 8; ++i) accX[i] = (f32x4){0.f,0.f,0.f,0.f};

    // ---- phase 0: C0 = X ks0,ks1 (gathers still in flight) ----
    WAITV(12);                                // C0 done; C1+gathers in flight
    BAR();
    {
        const short* wb = &Wb[0][0];
        PRIO1();
        #pragma unroll
        for (int ksl = 0; ksl < 2; ++ksl)
            #pragma unroll
            for (int nt = 0; nt < 8; ++nt) {
                bf16x8 b = *reinterpret_cast<const bf16x8*>(&wb[(ksl*8+nt)*512 + l*8]);
                accX[nt] = __builtin_amdgcn_mfma_f32_16x16x32_bf16(af_a[ksl], b, accX[nt], 0, 0, 0);
            }
        PRIO0();
    }

    // ---- phase 1: C1 = X ks2,ks3 ; then fold gathers + bias + LN ----
    WAITV(8);                                 // C1 done; gathers in flight
    BAR();
    {
        const short* wb = &Wb[1][0];
        PRIO1();
        #pragma unroll
        for (int ksl = 0; ksl < 2; ++ksl)
            #pragma unroll
            for (int nt = 0; nt < 8; ++nt) {
                bf16x8 b = *reinterpret_cast<const bf16x8*>(&wb[(ksl*8+nt)*512 + l*8]);
                accX[nt] = __builtin_amdgcn_mfma_f32_16x16x32_bf16(af_a[2+ksl], b, accX[nt], 0, 0, 0);
            }
        PRIO0();
    }
    WAITV(0);                                 // gathers done (hidden under 2 phases)
    #pragma unroll
    for (int r = 0; r < 4; ++r)
        #pragma unroll
        for (int nt = 0; nt < 8; ++nt)
            accX[nt][r] += bf2f((unsigned short)gaV[r][nt]) + bf2f((unsigned short)gbV[r][nt]);
    // bias + LayerNorm (register/LDS only)
    #pragma unroll
    for (int nt = 0; nt < 8; ++nt) {
        float bv = sBias[(nt<<4) + ln];
        #pragma unroll
        for (int r = 0; r < 4; ++r) accX[nt][r] += bv;
    }
    #pragma unroll
    for (int r = 0; r < 4; ++r) {
        float p = 0.f, q = 0.f;
        #pragma unroll
        for (int nt = 0; nt < 8; ++nt) { float x = accX[nt][r]; p += x; q += x*x; }
        #pragma unroll
        for (int d2 = 1; d2 < 16; d2 <<= 1) { p += __shfl_xor(p, d2); q += __shfl_xor(q, d2); }
        float mean = p * 0.0078125f;
        float var  = q * 0.0078125f - mean * mean;
        float rstd = rsqrtf(var + 1e-6f);
        #pragma unroll
        for (int nt = 0; nt < 8; ++nt)
            accX[nt][r] = (accX[nt][r] - mean) * rstd;
    }
    // temb loads then stage C2 (temb older than C2's stage ops)
    #pragma unroll
    for (int k2 = 0; k2 < 4; ++k2) {
        tf[2*k2]   = ld4(temb + (long)em * 128 + k2*32 + kb);
        tf[2*k2+1] = ld4(temb + (long)em * 128 + k2*32 + kb + 4);
    }
    STAGE16(2);
    WAITV(4);                                 // temb done; C2's 4 stage ops in flight
    bf16x8 ttf[4];
    #pragma unroll
    for (int k2 = 0; k2 < 4; ++k2) {
        float4 va = tf[2*k2], vb = tf[2*k2+1];
        va.x=silu1(va.x); va.y=silu1(va.y); va.z=silu1(va.z); va.w=silu1(va.w);
        vb.x=silu1(vb.x); vb.y=silu1(vb.y); vb.z=silu1(vb.z); vb.w=silu1(vb.w);
        ttf[k2] = pack8(va, vb);
    }

    // ---- phases 2..5: T big chunks C2..C5 (2 t-values each), FiLM inline ----
    #pragma unroll
    for (int tc = 0; tc < 4; ++tc) {
        WAITV(0);
        BAR();
        STAGE16(3 + tc);                      // C3..C6
        const short* wb = &Wb[tc & 1][0];     // (2+tc)&1 == tc&1
        #pragma unroll
        for (int tl = 0; tl < 2; ++tl) {
            const int t = 2*tc + tl;
            #pragma unroll
            for (int jj = 0; jj < 2; ++jj) {
                f32x4 tt = (f32x4){0.f,0.f,0.f,0.f};
                PRIO1();
                #pragma unroll
                for (int ks = 0; ks < 4; ++ks) {
                    bf16x8 b = *reinterpret_cast<const bf16x8*>(&wb[(tl*8 + jj*4 + ks)*512 + l*8]);
                    tt = __builtin_amdgcn_mfma_f32_16x16x32_bf16(ttf[ks], b, tt, 0, 0, 0);
                }
                PRIO0();
                if (t < 4) {
                    const int jx = 2*t + jj;
                    float bsc = sBias[384 + (jx<<4) + ln];
                    #pragma unroll
                    for (int r = 0; r < 4; ++r) accX[jx][r] *= (1.f + tt[r] + bsc);
                } else {
                    const int jx = 2*(t-4) + jj;
                    float bsh = sBias[256 + (jx<<4) + ln];
                    #pragma unroll
                    for (int r = 0; r < 4; ++r) accX[jx][r] += tt[r] + bsh;
                }
            }
        }
    }

    // ---- transpose inv -> A-layout in own slice of Wb[1] (C5 consumed; C7
    //      will overwrite this exact slice only after phase-6's barrier) ----
    short* tbW = &Wb[1][w * 2048];
    bf16x8 iaf[4];
    WAITL();                                  // own ds_reads of C5 retired
    BAR();                                    // all waves done with C5
    #pragma unroll
    for (int hpx = 0; hpx < 2; ++hpx) {
        #pragma unroll
        for (int nt4 = 0; nt4 < 4; ++nt4) {
            const int nt = hpx*4 + nt4;
            #pragma unroll
            for (int r = 0; r < 4; ++r)
                tbW[tswz((lg<<2) + r, (nt4<<4) + ln)] = f2bf(accX[nt][r]);
        }
        #pragma unroll
        for (int k2 = 0; k2 < 2; ++k2)
            iaf[hpx*2 + k2] = *reinterpret_cast<const bf16x8*>(&tbW[tswz(ln, (k2<<5) + kb)]);
    }
    WAITL();                                  // transpose reads done before stage(C7)

    // ---- phase 6: C6 = W1 u0,u1 ----
    f32x4 accY[8];
    #pragma unroll
    for (int i = 0; i < 8; ++i) accY[i] = (f32x4){0.f,0.f,0.f,0.f};
    WAITV(0);
    BAR();
    STAGE16(7);
    {
        const short* wb = &Wb[0][0];
        PRIO1();
        #pragma unroll
        for (int ul = 0; ul < 2; ++ul)
            #pragma unroll
            for (int s = 0; s < 2; ++s) {
                const int nt = 2*ul + s;
                #pragma unroll
                for (int ks = 0; ks < 4; ++ks) {
                    bf16x8 b = *reinterpret_cast<const bf16x8*>(&wb[(ul*8 + s*4 + ks)*512 + l*8]);
                    accY[nt] = __builtin_amdgcn_mfma_f32_16x16x32_bf16(iaf[ks], b, accY[nt], 0, 0, 0);
                }
            }
        PRIO0();
    }

    // ---- phase 7: C7 = W1 u2,u3 ; stage W2 ----
    WAITV(0);
    BAR();
    STAGEW2();                                // 4 frags -> Wb[0]
    {
        const short* wb = &Wb[1][0];
        PRIO1();
        #pragma unroll
        for (int ul = 0; ul < 2; ++ul)
            #pragma unroll
            for (int s = 0; s < 2; ++s) {
                const int nt = 4 + 2*ul + s;
                #pragma unroll
                for (int ks = 0; ks < 4; ++ks) {
                    bf16x8 b = *reinterpret_cast<const bf16x8*>(&wb[(ul*8 + s*4 + ks)*512 + l*8]);
                    accY[nt] = __builtin_amdgcn_mfma_f32_16x16x32_bf16(iaf[ks], b, accY[nt], 0, 0, 0);
                }
            }
        PRIO0();
    }

    // ---- silu + transpose back in own slice of Wb[1] (C7 consumed) ----
    bf16x8 yaf[4];
    WAITL();
    BAR();
    #pragma unroll
    for (int hpx = 0; hpx < 2; ++hpx) {
        #pragma unroll
        for (int nt4 = 0; nt4 < 4; ++nt4) {
            const int nt = hpx*4 + nt4;
            float bv = sBias[128 + (nt<<4) + ln];
            #pragma unroll
            for (int r = 0; r < 4; ++r)
                tbW[tswz((lg<<2) + r, (nt4<<4) + ln)] = f2bf(silu1(accY[nt][r] + bv));
        }
        #pragma unroll
        for (int k2 = 0; k2 < 2; ++k2)
            yaf[hpx*2 + k2] = *reinterpret_cast<const bf16x8*>(&tbW[tswz(ln, (k2<<5) + kb)]);
    }

    // ---- W2 stage (Wb[0]) ----
    WAITV(0);
    BAR();
    f32x4 accZ = (f32x4){0.f,0.f,0.f,0.f};
    {
        const short* wb = &Wb[0][0];
        PRIO1();
        #pragma unroll
        for (int ks = 0; ks < 4; ++ks) {
            bf16x8 b = *reinterpret_cast<const bf16x8*>(&wb[ks*512 + l*8]);
            accZ = __builtin_amdgcn_mfma_f32_16x16x32_bf16(yaf[ks], b, accZ, 0, 0, 0);
        }
        PRIO0();
    }

    // ---- epilogue ----
    {
        float dx = pos[ir*3+0] - pos[ic*3+0];
        float dy = pos[ir*3+1] - pos[ic*3+1];
        float dz = pos[ir*3+2] - pos[ic*3+2];
        float a0 = adj[em*3+0], a1 = adj[em*3+1], a2 = adj[em*3+2];
        float nrm = sqrtf(dx*dx + dy*dy + dz*dz);
        float sc  = cscale[0] / fmaxf(nrm, 1e-8f);
        float cdx = dx * sc, cdy = dy * sc, cdz = dz * sc;
        #pragma unroll
        for (int r = 0; r < 4; ++r) {
            const int m = (lg<<2) + r;
            float z  = tanh1(accZ[r]);
            float w0 = __shfl(a0, m), w1 = __shfl(a1, m), w2 = __shfl(a2, m);
            int   irm  = __shfl(ir, m);
            float cdxm = __shfl(cdx, m), cdym = __shfl(cdy, m), cdzm = __shfl(cdz, m);
            float wt = (ln == 0) ? 1.0f : (ln == 1 ? w0 : (ln == 2 ? w1 : (ln == 3 ? w2 : 0.0f)));
            float v = z * wt;
            v += __shfl_xor(v, 1);
            v += __shfl_xor(v, 2);
            float s = v * 0.25f;
            if (ln < 3) {
                float cdc = (ln == 0) ? cdxm : (ln == 1 ? cdym : cdzm);
                atomicAdd(&out[(long)irm*3 + ln], cdc * s);
            }
        }
    }
    #undef STAGE16
    #undef STAGEW2
}

// ============ FALLBACK PATH (R14, proven 552 us) ===============================
__global__ void pack_weights_fb(const float* __restrict__ Wt,
                                const float* __restrict__ Win,
                                const float* __restrict__ W1,
                                const float* __restrict__ W2,
                                short* __restrict__ ws)
{
    int gid = blockIdx.x * 256 + threadIdx.x;
    if (gid >= 196 * 512) return;
    int frag = gid >> 9, within = gid & 511;
    int l = within >> 3, j = within & 7;
    int lg = l >> 4, ln = l & 15;
    int krow = (lg << 3) + j;
    float v;
    if (frag < 96) {
        int cs = frag >> 3, nt = frag & 7;
        int seg = cs >> 2, ks = cs & 3;
        int base = (seg == 0) ? 256 : (seg == 1) ? 0 : 128;
        int k = base + ks * 32 + krow;
        v = Win[k * 128 + nt * 16 + ln];
    } else if (frag < 160) {
        int t = frag - 96, ch = t >> 3, sub = t & 7;
        int jj = sub >> 2, ks = sub & 3;
        int jcol = (ch < 4) ? (8 + 2 * ch + jj) : (2 * (ch - 4) + jj);
        int k = ks * 32 + krow;
        v = Wt[k * 256 + jcol * 16 + ln];
    } else if (frag < 192) {
        int t = frag - 160, ch = t >> 3, sub = t & 7;
        int nt = 2 * ch + (sub >> 2), ks = sub & 3;
        int k = ks * 32 + krow;
        v = W1[k * 128 + nt * 16 + ln];
    } else {
        int ks = frag - 192;
        int k = ks * 32 + krow;
        v = (ln < 4) ? W2[k * 4 + ln] : 0.0f;
    }
    ws[gid] = f2bf(v);
}

__global__ void h_pack_kernel(const float* __restrict__ h, short* __restrict__ hbf) {
    long i = (long)(blockIdx.x * 256 + threadIdx.x) * 8;
    if (i >= (long)N_NODES * 128) return;
    float4 a = ld4(h + i), b = ld4(h + i + 4);
    *reinterpret_cast<bf16x8*>(hbf + i) = pack8(a, b);
}

template<bool HBF>
__global__ __launch_bounds__(256, 3)
void edge_kernel_fb(const float* __restrict__ h,
                    const short* __restrict__ hbf,
                    const float* __restrict__ pos,
                    const float* __restrict__ ea,
                    const float* __restrict__ dst_f,
                    const float* __restrict__ temb,
                    const float* __restrict__ adj,
                    const float* __restrict__ btime,
                    const float* __restrict__ bin,
                    const float* __restrict__ b1,
                    const float* __restrict__ cscale,
                    const int*   __restrict__ ei,
                    const short* __restrict__ ws,
                    float* __restrict__ out)
{
    __shared__ __align__(16) short Wb[3][4096];
    __shared__ float sBias[512];

    const int tid = threadIdx.x;
    const int w   = tid >> 6;
    const int l   = tid & 63;
    const int ln  = l & 15;
    const int lg  = l >> 4;
    const int kb  = lg << 3;
    const int e0w = blockIdx.x * 64 + w * 16;
    const int em  = e0w + ln;

    const int ir = ei[em];
    const int ic = ei[E_EDGES + em];

    #pragma unroll
    for (int i = 0; i < 2; ++i) {
        int idx = tid + i * 256;
        float v = (idx < 128) ? bin[idx] : (idx < 256) ? b1[idx - 128] : btime[idx - 256];
        sBias[idx] = v;
    }
    WAITL();

    #define STAGE8(p) { \
        const short* g_ = ws + (p) * 4096 + (w*2) * 512 + l * 8; \
        short* d_ = &Wb[(p) % 3][(w*2) * 512]; \
        stage_frag(g_, d_); \
        stage_frag(g_ + 512, d_ + 512); }
    #define STAGEW2() { \
        stage_frag(ws + 24 * 4096 + w * 512 + l * 8, &Wb[0][w * 512]); }

    float4 tf[8];
    #pragma unroll
    for (int k2 = 0; k2 < 4; ++k2) {
        const float* q = (k2 < 2) ? (ea    + (long)em*64 + k2*32 + kb)
                                  : (dst_f + (long)em*64 + (k2-2)*32 + kb);
        tf[2*k2]   = ld4(q);
        tf[2*k2+1] = ld4(q + 4);
    }
    bf16x8 af_b[4];
    if (HBF) {
        #pragma unroll
        for (int k2 = 0; k2 < 4; ++k2)
            af_b[k2] = *reinterpret_cast<const bf16x8*>(hbf + (long)ir * 128 + k2*32 + kb);
    } else {
        #pragma unroll
        for (int k2 = 0; k2 < 4; ++k2)
            af_b[k2] = pack8(ld4(h + (long)ir*128 + k2*32 + kb),
                             ld4(h + (long)ir*128 + k2*32 + kb + 4));
    }
    STAGE8(0);
    STAGE8(1);
    if (HBF) { WAITV(8); } else { WAITV(4); }
    bf16x8 af_a[4];
    #pragma unroll
    for (int k2 = 0; k2 < 4; ++k2) af_a[k2] = pack8(tf[2*k2], tf[2*k2+1]);

    f32x4 accX[8];
    #pragma unroll
    for (int i = 0; i < 8; ++i) accX[i] = (f32x4){0.f,0.f,0.f,0.f};
    bf16x8 af_c[4];

    #pragma unroll
    for (int c = 0; c < 12; ++c) {
        if (HBF) {
            if (c == 4 || c == 5) { WAITV(6); } else { WAITV(2); }
        } else {
            if (c == 4 || c == 5) { WAITV(10); } else { WAITV(2); }
        }
        BAR();
        if (c == 11) {
            #pragma unroll
            for (int k2 = 0; k2 < 4; ++k2) {
                tf[2*k2]   = ld4(temb + (long)em * 128 + k2*32 + kb);
                tf[2*k2+1] = ld4(temb + (long)em * 128 + k2*32 + kb + 4);
            }
        }
        STAGE8(c + 2);
        if (c == 3) {
            if (HBF) {
                #pragma unroll
                for (int k2 = 0; k2 < 4; ++k2)
                    af_c[k2] = *reinterpret_cast<const bf16x8*>(hbf + (long)ic * 128 + k2*32 + kb);
            } else {
                #pragma unroll
                for (int k2 = 0; k2 < 4; ++k2)
                    af_c[k2] = pack8(ld4(h + (long)ic*128 + k2*32 + kb),
                                     ld4(h + (long)ic*128 + k2*32 + kb + 4));
            }
        }
        {
            const int ks = c & 3;
            const bf16x8 a_use = (c < 4) ? af_a[ks] : (c < 8) ? af_b[ks] : af_c[ks];
            const short* wb = &Wb[c % 3][0];
            #pragma unroll
            for (int nt = 0; nt < 8; ++nt) {
                bf16x8 b = *reinterpret_cast<const bf16x8*>(&wb[nt*512 + l*8]);
                accX[nt] = __builtin_amdgcn_mfma_f32_16x16x32_bf16(a_use, b, accX[nt], 0, 0, 0);
            }
        }
    }

    #pragma unroll
    for (int nt = 0; nt < 8; ++nt) {
        float bv = sBias[(nt<<4) + ln];
        #pragma unroll
        for (int r = 0; r < 4; ++r) accX[nt][r] += bv;
    }
    #pragma unroll
    for (int r = 0; r < 4; ++r) {
        float p = 0.f, q = 0.f;
        #pragma unroll
        for (int nt = 0; nt < 8; ++nt) { float x = accX[nt][r]; p += x; q += x*x; }
        #pragma unroll
        for (int d2 = 1; d2 < 16; d2 <<= 1) { p += __shfl_xor(p, d2); q += __shfl_xor(q, d2); }
        float mean = p * 0.0078125f;
        float var  = q * 0.0078125f - mean * mean;
        float rstd = rsqrtf(var + 1e-6f);
        #pragma unroll
        for (int nt = 0; nt < 8; ++nt)
            accX[nt][r] = (accX[nt][r] - mean) * rstd;
    }

    WAITV(2);
    bf16x8 ttf[4];
    #pragma unroll
    for (int k2 = 0; k2 < 4; ++k2) {
        float4 va = tf[2*k2], vb = tf[2*k2+1];
        va.x=silu1(va.x); va.y=silu1(va.y); va.z=silu1(va.z); va.w=silu1(va.w);
        vb.x=silu1(vb.x); vb.y=silu1(vb.y); vb.z=silu1(vb.z); vb.w=silu1(vb.w);
        ttf[k2] = pack8(va, vb);
    }

    #pragma unroll
    for (int t = 0; t < 8; ++t) {
        WAITV(2);
        BAR();
        STAGE8(14 + t);
        {
            const short* wb = &Wb[(12 + t) % 3][0];
            #pragma unroll
            for (int jj = 0; jj < 2; ++jj) {
                f32x4 tt = (f32x4){0.f,0.f,0.f,0.f};
                #pragma unroll
                for (int ks = 0; ks < 4; ++ks) {
                    bf16x8 b = *reinterpret_cast<const bf16x8*>(&wb[(jj*4+ks)*512 + l*8]);
                    tt = __builtin_amdgcn_mfma_f32_16x16x32_bf16(ttf[ks], b, tt, 0, 0, 0);
                }
                if (t < 4) {
                    const int jx = 2*t + jj;
                    float bsc = sBias[384 + (jx<<4) + ln];
                    #pragma unroll
                    for (int r = 0; r < 4; ++r) accX[jx][r] *= (1.f + tt[r] + bsc);
                } else {
                    const int jx = 2*(t-4) + jj;
                    float bsh = sBias[256 + (jx<<4) + ln];
                    #pragma unroll
                    for (int r = 0; r < 4; ++r) accX[jx][r] += tt[r] + bsh;
                }
            }
        }
    }

    short* tbW = &Wb[1][w * 1024];
    bf16x8 iaf[4];
    WAITL();
    BAR();
    #pragma unroll
    for (int hpx = 0; hpx < 2; ++hpx) {
        #pragma unroll
        for (int nt4 = 0; nt4 < 4; ++nt4) {
            const int nt = hpx*4 + nt4;
            #pragma unroll
            for (int r = 0; r < 4; ++r)
                tbW[tswz((lg<<2) + r, (nt4<<4) + ln)] = f2bf(accX[nt][r]);
        }
        #pragma unroll
        for (int k2 = 0; k2 < 2; ++k2)
            iaf[hpx*2 + k2] = *reinterpret_cast<const bf16x8*>(&tbW[tswz(ln, (k2<<5) + kb)]);
    }
    WAITL();

    f32x4 accY[8];
    #pragma unroll
    for (int i = 0; i < 8; ++i) accY[i] = (f32x4){0.f,0.f,0.f,0.f};
    #pragma unroll
    for (int u = 0; u < 4; ++u) {
        if (u < 3) { WAITV(2); } else { WAITV(1); }
        BAR();
        if (u < 2)       { STAGE8(22 + u); }
        else if (u == 2) { STAGEW2(); }
        {
            const short* wb = &Wb[(20 + u) % 3][0];
            #pragma unroll
            for (int s = 0; s < 2; ++s) {
                const int nt = 2*u + s;
                #pragma unroll
                for (int ks = 0; ks < 4; ++ks) {
                    bf16x8 b = *reinterpret_cast<const bf16x8*>(&wb[(s*4+ks)*512 + l*8]);
                    accY[nt] = __builtin_amdgcn_mfma_f32_16x16x32_bf16(iaf[ks], b, accY[nt], 0, 0, 0);
                }
            }
        }
    }

    bf16x8 yaf[4];
    WAITL();
    BAR();
    #pragma unroll
    for (int hpx = 0; hpx < 2; ++hpx) {
        #pragma unroll
        for (int nt4 = 0; nt4 < 4; ++nt4) {
            const int nt = hpx*4 + nt4;
            float bv = sBias[128 + (nt<<4) + ln];
            #pragma unroll
            for (int r = 0; r < 4; ++r)
                tbW[tswz((lg<<2) + r, (nt4<<4) + ln)] = f2bf(silu1(accY[nt][r] + bv));
        }
        #pragma unroll
        for (int k2 = 0; k2 < 2; ++k2)
            yaf[hpx*2 + k2] = *reinterpret_cast<const bf16x8*>(&tbW[tswz(ln, (k2<<5) + kb)]);
    }

    WAITV(0);
    BAR();
    f32x4 accZ = (f32x4){0.f,0.f,0.f,0.f};
    {
        const short* wb = &Wb[0][0];
        #pragma unroll
        for (int ks = 0; ks < 4; ++ks) {
            bf16x8 b = *reinterpret_cast<const bf16x8*>(&wb[ks*512 + l*8]);
            accZ = __builtin_amdgcn_mfma_f32_16x16x32_bf16(yaf[ks], b, accZ, 0, 0, 0);
        }
    }

    {
        float dx = pos[ir*3+0] - pos[ic*3+0];
        float dy = pos[ir*3+1] - pos[ic*3+1];
        float dz = pos[ir*3+2] - pos[ic*3+2];
        float a0 = adj[em*3+0], a1 = adj[em*3+1], a2 = adj[em*3+2];
        float nrm = sqrtf(dx*dx + dy*dy + dz*dz);
        float sc  = cscale[0] / fmaxf(nrm, 1e-8f);
        float cdx = dx * sc, cdy = dy * sc, cdz = dz * sc;
        #pragma unroll
        for (int r = 0; r < 4; ++r) {
            const int m = (lg<<2) + r;
            float z  = tanh1(accZ[r]);
            float w0 = __shfl(a0, m), w1 = __shfl(a1, m), w2 = __shfl(a2, m);
            int   irm  = __shfl(ir, m);
            float cdxm = __shfl(cdx, m), cdym = __shfl(cdy, m), cdzm = __shfl(cdz, m);
            float wt = (ln == 0) ? 1.0f : (ln == 1 ? w0 : (ln == 2 ? w1 : (ln == 3 ? w2 : 0.0f)));
            float v = z * wt;
            v += __shfl_xor(v, 1);
            v += __shfl_xor(v, 2);
            float s = v * 0.25f;
            if (ln < 3) {
                float cdc = (ln == 0) ? cdxm : (ln == 1 ? cdym : cdzm);
                atomicAdd(&out[(long)irm*3 + ln], cdc * s);
            }
        }
    }
    #undef STAGE8
    #undef STAGEW2
}

extern "C" void kernel_launch(void* const* d_in, const int* in_sizes, int n_in,
                              void* d_out, int out_size, void* d_ws, size_t ws_size,
                              hipStream_t stream) {
    const float* h     = (const float*)d_in[0];
    const float* pos   = (const float*)d_in[1];
    const float* ea    = (const float*)d_in[2];
    const float* dist  = (const float*)d_in[3];
    const float* temb  = (const float*)d_in[4];
    const float* adj   = (const float*)d_in[5];
    const float* Wt    = (const float*)d_in[6];
    const float* bt    = (const float*)d_in[7];
    const float* Win   = (const float*)d_in[8];
    const float* bin   = (const float*)d_in[9];
    const float* W1    = (const float*)d_in[10];
    const float* b1    = (const float*)d_in[11];
    const float* W2    = (const float*)d_in[12];
    const float* cs    = (const float*)d_in[13];
    const int*   ei    = (const int*)d_in[14];
    float*       out   = (float*)d_out;
    short*       ws    = (short*)d_ws;

    const size_t WF_SHORTS = 196 * 512;                  // 100352
    const size_t HP_SHORTS = (size_t)N_NODES * 256;      // 25.6M (Hpre bf16)
    const size_t HB_SHORTS = (size_t)N_NODES * 128;      // 12.8M (fallback hbf)
    const bool factored = ws_size >= (WF_SHORTS + HP_SHORTS) * sizeof(short);

    hipMemcpyAsync(out, pos, (size_t)out_size * sizeof(float),
                   hipMemcpyDeviceToDevice, stream);

    if (factored) {
        short* hp = ws + WF_SHORTS;
        pack_weights_f<<<(196*512 + 255) / 256, 256, 0, stream>>>(Wt, Win, W1, W2, ws);
        hpre_kernel<<<(N_NODES + 63) / 64, 256, 0, stream>>>(h, ws, hp);
        edge_kernel_f<<<E_EDGES / 64, 256, 0, stream>>>(
            pos, ea, dist, temb, adj, bt, bin, b1, cs, ei, ws,
            (const unsigned short*)hp, out);
    } else {
        const bool use_hbf = ws_size >= (WF_SHORTS + HB_SHORTS) * sizeof(short);
        short* hbf = ws + WF_SHORTS;
        pack_weights_fb<<<(196*512 + 255) / 256, 256, 0, stream>>>(Wt, Win, W1, W2, ws);
        if (use_hbf) {
            h_pack_kernel<<<(int)(HB_SHORTS / 8 / 256), 256, 0, stream>>>(h, hbf);
            edge_kernel_fb<true><<<E_EDGES / 64, 256, 0, stream>>>(
                h, hbf, pos, ea, dist, temb, adj, bt, bin, b1, cs, ei, ws, out);
        } else {
            edge_kernel_fb<false><<<E_EDGES / 64, 256, 0, stream>>>(
                h, hbf, pos, ea, dist, temb, adj, bt, bin, b1, cs, ei, ws, out);
        }
    }
}

// Round 20
// 510.566 us; speedup vs baseline: 1.0677x; 1.0677x over previous
//
#include <hip/hip_runtime.h>
#include <hip/hip_bf16.h>

#define E_EDGES 1000000
#define N_NODES 100000

typedef __attribute__((ext_vector_type(8))) short bf16x8;
typedef __attribute__((ext_vector_type(4))) float f32x4;

#define WAITV(N) asm volatile("s_waitcnt vmcnt(" #N ")" ::: "memory")
#define WAITL()  asm volatile("s_waitcnt lgkmcnt(0)" ::: "memory")
#define BAR()    __builtin_amdgcn_s_barrier()
#define PRIO1()  __builtin_amdgcn_s_setprio(1)
#define PRIO0()  __builtin_amdgcn_s_setprio(0)

__device__ __forceinline__ short f2bf(float f) {
    union { __bf16 b; short s; } u;
    u.b = (__bf16)f;
    return u.s;
}
__device__ __forceinline__ bf16x8 pack8(float4 a, float4 b) {
    bf16x8 r;
    r[0]=f2bf(a.x); r[1]=f2bf(a.y); r[2]=f2bf(a.z); r[3]=f2bf(a.w);
    r[4]=f2bf(b.x); r[5]=f2bf(b.y); r[6]=f2bf(b.z); r[7]=f2bf(b.w);
    return r;
}
__device__ __forceinline__ float4 ld4(const float* p) {
    return *reinterpret_cast<const float4*>(p);
}
__device__ __forceinline__ float silu1(float x) { return x / (1.f + __expf(-x)); }
__device__ __forceinline__ float tanh1(float x) {
    float e = __expf(2.f * x);
    return 1.f - 2.f / (e + 1.f);
}
__device__ __forceinline__ float bf2f(unsigned short u) {
    return __uint_as_float(((unsigned)u) << 16);
}

__device__ __forceinline__ void stage_frag(const short* gsrc, short* ldst) {
    __builtin_amdgcn_global_load_lds(
        (const __attribute__((address_space(1))) void*)gsrc,
        (__attribute__((address_space(3))) void*)ldst, 16, 0, 0);
}

// swizzled transpose index (shorts) within a per-wave 16x64 slice
__device__ __forceinline__ int tswz(int row, int colS) {
    return (row * 64 + colS) ^ ((row & 7) << 3);
}

// ============ FACTORED PATH ====================================================
// pack layout: frags 0-31 X (Win rows 256..383, ks*8+nt), 32-95 W_time,
// 96-127 W1, 128-131 W2, 132-195 hpre weights.
// Hpre is stored GATHER-ORDERED: position of col c (within each 128-half) is
// (c&15)*8 + (c>>4), so an edge lane reads its 8 needed values as ONE 16B load.
__global__ void pack_weights_f(const float* __restrict__ Wt,
                               const float* __restrict__ Win,
                               const float* __restrict__ W1,
                               const float* __restrict__ W2,
                               short* __restrict__ ws)
{
    int gid = blockIdx.x * 256 + threadIdx.x;
    if (gid >= 196 * 512) return;
    int frag = gid >> 9, within = gid & 511;
    int l = within >> 3, j = within & 7;
    int lg = l >> 4, ln = l & 15;
    int krow = (lg << 3) + j;
    float v;
    if (frag < 32) {                         // X: Win rows 256..383
        int ks = frag >> 3, nt = frag & 7;
        v = Win[(256 + ks * 32 + krow) * 128 + nt * 16 + ln];
    } else if (frag < 96) {                  // W_time
        int t = frag - 32, ch = t >> 3, sub = t & 7;
        int jj = sub >> 2, ks = sub & 3;
        int jcol = (ch < 4) ? (8 + 2 * ch + jj) : (2 * (ch - 4) + jj);
        v = Wt[(ks * 32 + krow) * 256 + jcol * 16 + ln];
    } else if (frag < 128) {                 // W1
        int t = frag - 96, ch = t >> 3, sub = t & 7;
        int nt = 2 * ch + (sub >> 2), ks = sub & 3;
        v = W1[(ks * 32 + krow) * 128 + nt * 16 + ln];
    } else if (frag < 132) {                 // W2 padded
        int ks = frag - 128;
        v = (ln < 4) ? W2[(ks * 32 + krow) * 4 + ln] : 0.0f;
    } else {                                 // hpre weights: Win rows 0..255
        int q = frag - 132;
        int ntc = q >> 2, ks = q & 3;
        int base = (ntc < 8) ? 0 : 128;
        v = Win[(base + ks * 32 + krow) * 128 + (ntc & 7) * 16 + ln];
    }
    ws[gid] = f2bf(v);
}

// Hpre[n] = h[n] @ Win[0:256], stored gather-ordered (see above).
__global__ __launch_bounds__(256)
void hpre_kernel(const float* __restrict__ h, const short* __restrict__ ws,
                 short* __restrict__ hp)
{
    const int tid = threadIdx.x;
    const int w   = tid >> 6;
    const int l   = tid & 63;
    const int ln  = l & 15;
    const int lg  = l >> 4;
    const int kb  = lg << 3;
    const int nb  = blockIdx.x * 64 + w * 16;
    const int nm  = min(nb + ln, N_NODES - 1);

    bf16x8 af[4];
    #pragma unroll
    for (int ks = 0; ks < 4; ++ks)
        af[ks] = pack8(ld4(h + (long)nm * 128 + ks*32 + kb),
                       ld4(h + (long)nm * 128 + ks*32 + kb + 4));
    const short* wsp = ws + 132 * 512;
    #pragma unroll
    for (int ntc = 0; ntc < 16; ++ntc) {
        f32x4 acc = (f32x4){0.f,0.f,0.f,0.f};
        #pragma unroll
        for (int ks = 0; ks < 4; ++ks) {
            bf16x8 b = *reinterpret_cast<const bf16x8*>(&wsp[(ntc*4+ks)*512 + l*8]);
            acc = __builtin_amdgcn_mfma_f32_16x16x32_bf16(af[ks], b, acc, 0, 0, 0);
        }
        // gather-ordered store: col c = ntc*16 + ln -> half*128 + ln*8 + (ntc&7)
        const int off = ((ntc < 8) ? 0 : 128) + ln * 8 + (ntc & 7);
        #pragma unroll
        for (int r = 0; r < 4; ++r) {
            int node = nb + (lg<<2) + r;
            if (node < N_NODES)
                hp[(long)node * 256 + off] = f2bf(acc[r]);
        }
    }
}

// factored edge kernel: 8 BIG phases (16 KB chunks, depth-2 dbuf) + W2.
// R20 = R18 schedule (64 VGPR, prologue gathers) + setprio around MFMA clusters.
__global__ __launch_bounds__(256, 3)
void edge_kernel_f(const float* __restrict__ pos,
                   const float* __restrict__ ea,
                   const float* __restrict__ dst_f,
                   const float* __restrict__ temb,
                   const float* __restrict__ adj,
                   const float* __restrict__ btime,
                   const float* __restrict__ bin,
                   const float* __restrict__ b1,
                   const float* __restrict__ cscale,
                   const int*   __restrict__ ei,
                   const short* __restrict__ ws,
                   const unsigned short* __restrict__ hp,
                   float* __restrict__ out)
{
    __shared__ __align__(16) short Wb[2][8192];   // 2 x 16 KB big-chunk dbuf
    __shared__ float sBias[512];

    const int tid = threadIdx.x;
    const int w   = tid >> 6;
    const int l   = tid & 63;
    const int ln  = l & 15;
    const int lg  = l >> 4;
    const int kb  = lg << 3;
    const int e0w = blockIdx.x * 64 + w * 16;
    const int em  = e0w + ln;

    const int ir = ei[em];
    const int ic = ei[E_EDGES + em];

    #pragma unroll
    for (int i = 0; i < 2; ++i) {
        int idx = tid + i * 256;
        float v = (idx < 128) ? bin[idx] : (idx < 256) ? b1[idx - 128] : btime[idx - 256];
        sBias[idx] = v;
    }
    WAITL();

    // big chunk C (16 frags): wave w stages frags 4w..4w+3 (its own 4 KB slice)
    #define STAGE16(C) { \
        const short* g_ = ws + (C) * 8192 + (w*4) * 512 + l * 8; \
        short* d_ = &Wb[(C) & 1][(w*4) * 512]; \
        stage_frag(g_, d_); \
        stage_frag(g_ + 512, d_ + 512); \
        stage_frag(g_ + 1024, d_ + 1024); \
        stage_frag(g_ + 1536, d_ + 1536); }
    #define STAGEW2() { \
        stage_frag(ws + 128 * 512 + w * 512 + l * 8, &Wb[0][w * 512]); }

    // C-layout row -> edge indices via shfl
    int irg[4], icg[4];
    #pragma unroll
    for (int r = 0; r < 4; ++r) {
        irg[r] = __shfl(ir, (lg<<2) + r);
        icg[r] = __shfl(ic, (lg<<2) + r);
    }

    // ---- prologue: 8 vectorized Hpre gathers + ea|dist f32 loads + C0,C1 ----
    bf16x8 gaV[4], gbV[4];                    // gather-ordered: one 16B load each
    #pragma unroll
    for (int r = 0; r < 4; ++r) {
        gaV[r] = *reinterpret_cast<const bf16x8*>(hp + (long)irg[r]*256 + ln*8);
        gbV[r] = *reinterpret_cast<const bf16x8*>(hp + (long)icg[r]*256 + 128 + ln*8);
    }
    float4 tf[8];
    #pragma unroll
    for (int k2 = 0; k2 < 4; ++k2) {
        const float* q = (k2 < 2) ? (ea    + (long)em*64 + k2*32 + kb)
                                  : (dst_f + (long)em*64 + (k2-2)*32 + kb);
        tf[2*k2]   = ld4(q);
        tf[2*k2+1] = ld4(q + 4);
    }
    STAGE16(0);
    STAGE16(1);
    WAITV(8);                                 // gathers + tf retired; C0,C1 in flight

    f32x4 accX[8];
    #pragma unroll
    for (int r = 0; r < 4; ++r)
        #pragma unroll
        for (int nt = 0; nt < 8; ++nt)
            accX[nt][r] = bf2f((unsigned short)gaV[r][nt]) + bf2f((unsigned short)gbV[r][nt]);
    bf16x8 af_a[4];
    #pragma unroll
    for (int k2 = 0; k2 < 4; ++k2) af_a[k2] = pack8(tf[2*k2], tf[2*k2+1]);

    // ---- phase 0: C0 = X ks0,ks1 (no stage issue; dbuf full) ----
    WAITV(4);                                 // C0 done; C1 in flight
    BAR();
    {
        const short* wb = &Wb[0][0];
        PRIO1();
        #pragma unroll
        for (int ksl = 0; ksl < 2; ++ksl)
            #pragma unroll
            for (int nt = 0; nt < 8; ++nt) {
                bf16x8 b = *reinterpret_cast<const bf16x8*>(&wb[(ksl*8+nt)*512 + l*8]);
                accX[nt] = __builtin_amdgcn_mfma_f32_16x16x32_bf16(af_a[ksl], b, accX[nt], 0, 0, 0);
            }
        PRIO0();
    }

    // ---- phase 1: C1 = X ks2,ks3 ; issue temb then STAGE(C2); LN; ttf ----
    WAITV(0);
    BAR();
    #pragma unroll
    for (int k2 = 0; k2 < 4; ++k2) {         // temb loads (older than stage C2)
        tf[2*k2]   = ld4(temb + (long)em * 128 + k2*32 + kb);
        tf[2*k2+1] = ld4(temb + (long)em * 128 + k2*32 + kb + 4);
    }
    STAGE16(2);
    {
        const short* wb = &Wb[1][0];
        PRIO1();
        #pragma unroll
        for (int ksl = 0; ksl < 2; ++ksl)
            #pragma unroll
            for (int nt = 0; nt < 8; ++nt) {
                bf16x8 b = *reinterpret_cast<const bf16x8*>(&wb[(ksl*8+nt)*512 + l*8]);
                accX[nt] = __builtin_amdgcn_mfma_f32_16x16x32_bf16(af_a[2+ksl], b, accX[nt], 0, 0, 0);
            }
        PRIO0();
    }
    // bias + LayerNorm (register/LDS only)
    #pragma unroll
    for (int nt = 0; nt < 8; ++nt) {
        float bv = sBias[(nt<<4) + ln];
        #pragma unroll
        for (int r = 0; r < 4; ++r) accX[nt][r] += bv;
    }
    #pragma unroll
    for (int r = 0; r < 4; ++r) {
        float p = 0.f, q = 0.f;
        #pragma unroll
        for (int nt = 0; nt < 8; ++nt) { float x = accX[nt][r]; p += x; q += x*x; }
        #pragma unroll
        for (int d2 = 1; d2 < 16; d2 <<= 1) { p += __shfl_xor(p, d2); q += __shfl_xor(q, d2); }
        float mean = p * 0.0078125f;
        float var  = q * 0.0078125f - mean * mean;
        float rstd = rsqrtf(var + 1e-6f);
        #pragma unroll
        for (int nt = 0; nt < 8; ++nt)
            accX[nt][r] = (accX[nt][r] - mean) * rstd;
    }
    WAITV(4);                                 // temb done; C2's 4 stage ops in flight
    bf16x8 ttf[4];
    #pragma unroll
    for (int k2 = 0; k2 < 4; ++k2) {
        float4 va = tf[2*k2], vb = tf[2*k2+1];
        va.x=silu1(va.x); va.y=silu1(va.y); va.z=silu1(va.z); va.w=silu1(va.w);
        vb.x=silu1(vb.x); vb.y=silu1(vb.y); vb.z=silu1(vb.z); vb.w=silu1(vb.w);
        ttf[k2] = pack8(va, vb);
    }

    // ---- phases 2..5: T big chunks C2..C5 (2 t-values each), FiLM inline ----
    #pragma unroll
    for (int tc = 0; tc < 4; ++tc) {
        WAITV(0);
        BAR();
        STAGE16(3 + tc);                      // C3..C6
        const short* wb = &Wb[tc & 1][0];     // (2+tc)&1 == tc&1
        #pragma unroll
        for (int tl = 0; tl < 2; ++tl) {
            const int t = 2*tc + tl;
            #pragma unroll
            for (int jj = 0; jj < 2; ++jj) {
                f32x4 tt = (f32x4){0.f,0.f,0.f,0.f};
                PRIO1();
                #pragma unroll
                for (int ks = 0; ks < 4; ++ks) {
                    bf16x8 b = *reinterpret_cast<const bf16x8*>(&wb[(tl*8 + jj*4 + ks)*512 + l*8]);
                    tt = __builtin_amdgcn_mfma_f32_16x16x32_bf16(ttf[ks], b, tt, 0, 0, 0);
                }
                PRIO0();
                if (t < 4) {
                    const int jx = 2*t + jj;
                    float bsc = sBias[384 + (jx<<4) + ln];
                    #pragma unroll
                    for (int r = 0; r < 4; ++r) accX[jx][r] *= (1.f + tt[r] + bsc);
                } else {
                    const int jx = 2*(t-4) + jj;
                    float bsh = sBias[256 + (jx<<4) + ln];
                    #pragma unroll
                    for (int r = 0; r < 4; ++r) accX[jx][r] += tt[r] + bsh;
                }
            }
        }
    }

    // ---- transpose inv -> A-layout in own slice of Wb[1] (C5 consumed; C7
    //      will overwrite this exact slice only after phase-6's barrier) ----
    short* tbW = &Wb[1][w * 2048];
    bf16x8 iaf[4];
    WAITL();                                  // own ds_reads of C5 retired
    BAR();                                    // all waves done with C5
    #pragma unroll
    for (int hpx = 0; hpx < 2; ++hpx) {
        #pragma unroll
        for (int nt4 = 0; nt4 < 4; ++nt4) {
            const int nt = hpx*4 + nt4;
            #pragma unroll
            for (int r = 0; r < 4; ++r)
                tbW[tswz((lg<<2) + r, (nt4<<4) + ln)] = f2bf(accX[nt][r]);
        }
        #pragma unroll
        for (int k2 = 0; k2 < 2; ++k2)
            iaf[hpx*2 + k2] = *reinterpret_cast<const bf16x8*>(&tbW[tswz(ln, (k2<<5) + kb)]);
    }
    WAITL();                                  // transpose reads done before stage(C7)

    // ---- phase 6: C6 = W1 u0,u1 ----
    f32x4 accY[8];
    #pragma unroll
    for (int i = 0; i < 8; ++i) accY[i] = (f32x4){0.f,0.f,0.f,0.f};
    WAITV(0);
    BAR();
    STAGE16(7);
    {
        const short* wb = &Wb[0][0];
        PRIO1();
        #pragma unroll
        for (int ul = 0; ul < 2; ++ul)
            #pragma unroll
            for (int s = 0; s < 2; ++s) {
                const int nt = 2*ul + s;
                #pragma unroll
                for (int ks = 0; ks < 4; ++ks) {
                    bf16x8 b = *reinterpret_cast<const bf16x8*>(&wb[(ul*8 + s*4 + ks)*512 + l*8]);
                    accY[nt] = __builtin_amdgcn_mfma_f32_16x16x32_bf16(iaf[ks], b, accY[nt], 0, 0, 0);
                }
            }
        PRIO0();
    }

    // ---- phase 7: C7 = W1 u2,u3 ; stage W2 ----
    WAITV(0);
    BAR();
    STAGEW2();                                // 4 frags -> Wb[0]
    {
        const short* wb = &Wb[1][0];
        PRIO1();
        #pragma unroll
        for (int ul = 0; ul < 2; ++ul)
            #pragma unroll
            for (int s = 0; s < 2; ++s) {
                const int nt = 4 + 2*ul + s;
                #pragma unroll
                for (int ks = 0; ks < 4; ++ks) {
                    bf16x8 b = *reinterpret_cast<const bf16x8*>(&wb[(ul*8 + s*4 + ks)*512 + l*8]);
                    accY[nt] = __builtin_amdgcn_mfma_f32_16x16x32_bf16(iaf[ks], b, accY[nt], 0, 0, 0);
                }
            }
        PRIO0();
    }

    // ---- silu + transpose back in own slice of Wb[1] (C7 consumed) ----
    bf16x8 yaf[4];
    WAITL();
    BAR();
    #pragma unroll
    for (int hpx = 0; hpx < 2; ++hpx) {
        #pragma unroll
        for (int nt4 = 0; nt4 < 4; ++nt4) {
            const int nt = hpx*4 + nt4;
            float bv = sBias[128 + (nt<<4) + ln];
            #pragma unroll
            for (int r = 0; r < 4; ++r)
                tbW[tswz((lg<<2) + r, (nt4<<4) + ln)] = f2bf(silu1(accY[nt][r] + bv));
        }
        #pragma unroll
        for (int k2 = 0; k2 < 2; ++k2)
            yaf[hpx*2 + k2] = *reinterpret_cast<const bf16x8*>(&tbW[tswz(ln, (k2<<5) + kb)]);
    }

    // ---- W2 stage (Wb[0]) ----
    WAITV(0);
    BAR();
    f32x4 accZ = (f32x4){0.f,0.f,0.f,0.f};
    {
        const short* wb = &Wb[0][0];
        PRIO1();
        #pragma unroll
        for (int ks = 0; ks < 4; ++ks) {
            bf16x8 b = *reinterpret_cast<const bf16x8*>(&wb[ks*512 + l*8]);
            accZ = __builtin_amdgcn_mfma_f32_16x16x32_bf16(yaf[ks], b, accZ, 0, 0, 0);
        }
        PRIO0();
    }

    // ---- epilogue ----
    {
        float dx = pos[ir*3+0] - pos[ic*3+0];
        float dy = pos[ir*3+1] - pos[ic*3+1];
        float dz = pos[ir*3+2] - pos[ic*3+2];
        float a0 = adj[em*3+0], a1 = adj[em*3+1], a2 = adj[em*3+2];
        float nrm = sqrtf(dx*dx + dy*dy + dz*dz);
        float sc  = cscale[0] / fmaxf(nrm, 1e-8f);
        float cdx = dx * sc, cdy = dy * sc, cdz = dz * sc;
        #pragma unroll
        for (int r = 0; r < 4; ++r) {
            const int m = (lg<<2) + r;
            float z  = tanh1(accZ[r]);
            float w0 = __shfl(a0, m), w1 = __shfl(a1, m), w2 = __shfl(a2, m);
            int   irm  = __shfl(ir, m);
            float cdxm = __shfl(cdx, m), cdym = __shfl(cdy, m), cdzm = __shfl(cdz, m);
            float wt = (ln == 0) ? 1.0f : (ln == 1 ? w0 : (ln == 2 ? w1 : (ln == 3 ? w2 : 0.0f)));
            float v = z * wt;
            v += __shfl_xor(v, 1);
            v += __shfl_xor(v, 2);
            float s = v * 0.25f;
            if (ln < 3) {
                float cdc = (ln == 0) ? cdxm : (ln == 1 ? cdym : cdzm);
                atomicAdd(&out[(long)irm*3 + ln], cdc * s);
            }
        }
    }
    #undef STAGE16
    #undef STAGEW2
}

// ============ FALLBACK PATH (R14, proven 552 us) ===============================
__global__ void pack_weights_fb(const float* __restrict__ Wt,
                                const float* __restrict__ Win,
                                const float* __restrict__ W1,
                                const float* __restrict__ W2,
                                short* __restrict__ ws)
{
    int gid = blockIdx.x * 256 + threadIdx.x;
    if (gid >= 196 * 512) return;
    int frag = gid >> 9, within = gid & 511;
    int l = within >> 3, j = within & 7;
    int lg = l >> 4, ln = l & 15;
    int krow = (lg << 3) + j;
    float v;
    if (frag < 96) {
        int cs = frag >> 3, nt = frag & 7;
        int seg = cs >> 2, ks = cs & 3;
        int base = (seg == 0) ? 256 : (seg == 1) ? 0 : 128;
        int k = base + ks * 32 + krow;
        v = Win[k * 128 + nt * 16 + ln];
    } else if (frag < 160) {
        int t = frag - 96, ch = t >> 3, sub = t & 7;
        int jj = sub >> 2, ks = sub & 3;
        int jcol = (ch < 4) ? (8 + 2 * ch + jj) : (2 * (ch - 4) + jj);
        int k = ks * 32 + krow;
        v = Wt[k * 256 + jcol * 16 + ln];
    } else if (frag < 192) {
        int t = frag - 160, ch = t >> 3, sub = t & 7;
        int nt = 2 * ch + (sub >> 2), ks = sub & 3;
        int k = ks * 32 + krow;
        v = W1[k * 128 + nt * 16 + ln];
    } else {
        int ks = frag - 192;
        int k = ks * 32 + krow;
        v = (ln < 4) ? W2[k * 4 + ln] : 0.0f;
    }
    ws[gid] = f2bf(v);
}

__global__ void h_pack_kernel(const float* __restrict__ h, short* __restrict__ hbf) {
    long i = (long)(blockIdx.x * 256 + threadIdx.x) * 8;
    if (i >= (long)N_NODES * 128) return;
    float4 a = ld4(h + i), b = ld4(h + i + 4);
    *reinterpret_cast<bf16x8*>(hbf + i) = pack8(a, b);
}

template<bool HBF>
__global__ __launch_bounds__(256, 3)
void edge_kernel_fb(const float* __restrict__ h,
                    const short* __restrict__ hbf,
                    const float* __restrict__ pos,
                    const float* __restrict__ ea,
                    const float* __restrict__ dst_f,
                    const float* __restrict__ temb,
                    const float* __restrict__ adj,
                    const float* __restrict__ btime,
                    const float* __restrict__ bin,
                    const float* __restrict__ b1,
                    const float* __restrict__ cscale,
                    const int*   __restrict__ ei,
                    const short* __restrict__ ws,
                    float* __restrict__ out)
{
    __shared__ __align__(16) short Wb[3][4096];
    __shared__ float sBias[512];

    const int tid = threadIdx.x;
    const int w   = tid >> 6;
    const int l   = tid & 63;
    const int ln  = l & 15;
    const int lg  = l >> 4;
    const int kb  = lg << 3;
    const int e0w = blockIdx.x * 64 + w * 16;
    const int em  = e0w + ln;

    const int ir = ei[em];
    const int ic = ei[E_EDGES + em];

    #pragma unroll
    for (int i = 0; i < 2; ++i) {
        int idx = tid + i * 256;
        float v = (idx < 128) ? bin[idx] : (idx < 256) ? b1[idx - 128] : btime[idx - 256];
        sBias[idx] = v;
    }
    WAITL();

    #define STAGE8(p) { \
        const short* g_ = ws + (p) * 4096 + (w*2) * 512 + l * 8; \
        short* d_ = &Wb[(p) % 3][(w*2) * 512]; \
        stage_frag(g_, d_); \
        stage_frag(g_ + 512, d_ + 512); }
    #define STAGEW2() { \
        stage_frag(ws + 24 * 4096 + w * 512 + l * 8, &Wb[0][w * 512]); }

    float4 tf[8];
    #pragma unroll
    for (int k2 = 0; k2 < 4; ++k2) {
        const float* q = (k2 < 2) ? (ea    + (long)em*64 + k2*32 + kb)
                                  : (dst_f + (long)em*64 + (k2-2)*32 + kb);
        tf[2*k2]   = ld4(q);
        tf[2*k2+1] = ld4(q + 4);
    }
    bf16x8 af_b[4];
    if (HBF) {
        #pragma unroll
        for (int k2 = 0; k2 < 4; ++k2)
            af_b[k2] = *reinterpret_cast<const bf16x8*>(hbf + (long)ir * 128 + k2*32 + kb);
    } else {
        #pragma unroll
        for (int k2 = 0; k2 < 4; ++k2)
            af_b[k2] = pack8(ld4(h + (long)ir*128 + k2*32 + kb),
                             ld4(h + (long)ir*128 + k2*32 + kb + 4));
    }
    STAGE8(0);
    STAGE8(1);
    if (HBF) { WAITV(8); } else { WAITV(4); }
    bf16x8 af_a[4];
    #pragma unroll
    for (int k2 = 0; k2 < 4; ++k2) af_a[k2] = pack8(tf[2*k2], tf[2*k2+1]);

    f32x4 accX[8];
    #pragma unroll
    for (int i = 0; i < 8; ++i) accX[i] = (f32x4){0.f,0.f,0.f,0.f};
    bf16x8 af_c[4];

    #pragma unroll
    for (int c = 0; c < 12; ++c) {
        if (HBF) {
            if (c == 4 || c == 5) { WAITV(6); } else { WAITV(2); }
        } else {
            if (c == 4 || c == 5) { WAITV(10); } else { WAITV(2); }
        }
        BAR();
        if (c == 11) {
            #pragma unroll
            for (int k2 = 0; k2 < 4; ++k2) {
                tf[2*k2]   = ld4(temb + (long)em * 128 + k2*32 + kb);
                tf[2*k2+1] = ld4(temb + (long)em * 128 + k2*32 + kb + 4);
            }
        }
        STAGE8(c + 2);
        if (c == 3) {
            if (HBF) {
                #pragma unroll
                for (int k2 = 0; k2 < 4; ++k2)
                    af_c[k2] = *reinterpret_cast<const bf16x8*>(hbf + (long)ic * 128 + k2*32 + kb);
            } else {
                #pragma unroll
                for (int k2 = 0; k2 < 4; ++k2)
                    af_c[k2] = pack8(ld4(h + (long)ic*128 + k2*32 + kb),
                                     ld4(h + (long)ic*128 + k2*32 + kb + 4));
            }
        }
        {
            const int ks = c & 3;
            const bf16x8 a_use = (c < 4) ? af_a[ks] : (c < 8) ? af_b[ks] : af_c[ks];
            const short* wb = &Wb[c % 3][0];
            #pragma unroll
            for (int nt = 0; nt < 8; ++nt) {
                bf16x8 b = *reinterpret_cast<const bf16x8*>(&wb[nt*512 + l*8]);
                accX[nt] = __builtin_amdgcn_mfma_f32_16x16x32_bf16(a_use, b, accX[nt], 0, 0, 0);
            }
        }
    }

    #pragma unroll
    for (int nt = 0; nt < 8; ++nt) {
        float bv = sBias[(nt<<4) + ln];
        #pragma unroll
        for (int r = 0; r < 4; ++r) accX[nt][r] += bv;
    }
    #pragma unroll
    for (int r = 0; r < 4; ++r) {
        float p = 0.f, q = 0.f;
        #pragma unroll
        for (int nt = 0; nt < 8; ++nt) { float x = accX[nt][r]; p += x; q += x*x; }
        #pragma unroll
        for (int d2 = 1; d2 < 16; d2 <<= 1) { p += __shfl_xor(p, d2); q += __shfl_xor(q, d2); }
        float mean = p * 0.0078125f;
        float var  = q * 0.0078125f - mean * mean;
        float rstd = rsqrtf(var + 1e-6f);
        #pragma unroll
        for (int nt = 0; nt < 8; ++nt)
            accX[nt][r] = (accX[nt][r] - mean) * rstd;
    }

    WAITV(2);
    bf16x8 ttf[4];
    #pragma unroll
    for (int k2 = 0; k2 < 4; ++k2) {
        float4 va = tf[2*k2], vb = tf[2*k2+1];
        va.x=silu1(va.x); va.y=silu1(va.y); va.z=silu1(va.z); va.w=silu1(va.w);
        vb.x=silu1(vb.x); vb.y=silu1(vb.y); vb.z=silu1(vb.z); vb.w=silu1(vb.w);
        ttf[k2] = pack8(va, vb);
    }

    #pragma unroll
    for (int t = 0; t < 8; ++t) {
        WAITV(2);
        BAR();
        STAGE8(14 + t);
        {
            const short* wb = &Wb[(12 + t) % 3][0];
            #pragma unroll
            for (int jj = 0; jj < 2; ++jj) {
                f32x4 tt = (f32x4){0.f,0.f,0.f,0.f};
                #pragma unroll
                for (int ks = 0; ks < 4; ++ks) {
                    bf16x8 b = *reinterpret_cast<const bf16x8*>(&wb[(jj*4+ks)*512 + l*8]);
                    tt = __builtin_amdgcn_mfma_f32_16x16x32_bf16(ttf[ks], b, tt, 0, 0, 0);
                }
                if (t < 4) {
                    const int jx = 2*t + jj;
                    float bsc = sBias[384 + (jx<<4) + ln];
                    #pragma unroll
                    for (int r = 0; r < 4; ++r) accX[jx][r] *= (1.f + tt[r] + bsc);
                } else {
                    const int jx = 2*(t-4) + jj;
                    float bsh = sBias[256 + (jx<<4) + ln];
                    #pragma unroll
                    for (int r = 0; r < 4; ++r) accX[jx][r] += tt[r] + bsh;
                }
            }
        }
    }

    short* tbW = &Wb[1][w * 1024];
    bf16x8 iaf[4];
    WAITL();
    BAR();
    #pragma unroll
    for (int hpx = 0; hpx < 2; ++hpx) {
        #pragma unroll
        for (int nt4 = 0; nt4 < 4; ++nt4) {
            const int nt = hpx*4 + nt4;
            #pragma unroll
            for (int r = 0; r < 4; ++r)
                tbW[tswz((lg<<2) + r, (nt4<<4) + ln)] = f2bf(accX[nt][r]);
        }
        #pragma unroll
        for (int k2 = 0; k2 < 2; ++k2)
            iaf[hpx*2 + k2] = *reinterpret_cast<const bf16x8*>(&tbW[tswz(ln, (k2<<5) + kb)]);
    }
    WAITL();

    f32x4 accY[8];
    #pragma unroll
    for (int i = 0; i < 8; ++i) accY[i] = (f32x4){0.f,0.f,0.f,0.f};
    #pragma unroll
    for (int u = 0; u < 4; ++u) {
        if (u < 3) { WAITV(2); } else { WAITV(1); }
        BAR();
        if (u < 2)       { STAGE8(22 + u); }
        else if (u == 2) { STAGEW2(); }
        {
            const short* wb = &Wb[(20 + u) % 3][0];
            #pragma unroll
            for (int s = 0; s < 2; ++s) {
                const int nt = 2*u + s;
                #pragma unroll
                for (int ks = 0; ks < 4; ++ks) {
                    bf16x8 b = *reinterpret_cast<const bf16x8*>(&wb[(s*4+ks)*512 + l*8]);
                    accY[nt] = __builtin_amdgcn_mfma_f32_16x16x32_bf16(iaf[ks], b, accY[nt], 0, 0, 0);
                }
            }
        }
    }

    bf16x8 yaf[4];
    WAITL();
    BAR();
    #pragma unroll
    for (int hpx = 0; hpx < 2; ++hpx) {
        #pragma unroll
        for (int nt4 = 0; nt4 < 4; ++nt4) {
            const int nt = hpx*4 + nt4;
            float bv = sBias[128 + (nt<<4) + ln];
            #pragma unroll
            for (int r = 0; r < 4; ++r)
                tbW[tswz((lg<<2) + r, (nt4<<4) + ln)] = f2bf(silu1(accY[nt][r] + bv));
        }
        #pragma unroll
        for (int k2 = 0; k2 < 2; ++k2)
            yaf[hpx*2 + k2] = *reinterpret_cast<const bf16x8*>(&tbW[tswz(ln, (k2<<5) + kb)]);
    }

    WAITV(0);
    BAR();
    f32x4 accZ = (f32x4){0.f,0.f,0.f,0.f};
    {
        const short* wb = &Wb[0][0];
        #pragma unroll
        for (int ks = 0; ks < 4; ++ks) {
            bf16x8 b = *reinterpret_cast<const bf16x8*>(&wb[ks*512 + l*8]);
            accZ = __builtin_amdgcn_mfma_f32_16x16x32_bf16(yaf[ks], b, accZ, 0, 0, 0);
        }
    }

    {
        float dx = pos[ir*3+0] - pos[ic*3+0];
        float dy = pos[ir*3+1] - pos[ic*3+1];
        float dz = pos[ir*3+2] - pos[ic*3+2];
        float a0 = adj[em*3+0], a1 = adj[em*3+1], a2 = adj[em*3+2];
        float nrm = sqrtf(dx*dx + dy*dy + dz*dz);
        float sc  = cscale[0] / fmaxf(nrm, 1e-8f);
        float cdx = dx * sc, cdy = dy * sc, cdz = dz * sc;
        #pragma unroll
        for (int r = 0; r < 4; ++r) {
            const int m = (lg<<2) + r;
            float z  = tanh1(accZ[r]);
            float w0 = __shfl(a0, m), w1 = __shfl(a1, m), w2 = __shfl(a2, m);
            int   irm  = __shfl(ir, m);
            float cdxm = __shfl(cdx, m), cdym = __shfl(cdy, m), cdzm = __shfl(cdz, m);
            float wt = (ln == 0) ? 1.0f : (ln == 1 ? w0 : (ln == 2 ? w1 : (ln == 3 ? w2 : 0.0f)));
            float v = z * wt;
            v += __shfl_xor(v, 1);
            v += __shfl_xor(v, 2);
            float s = v * 0.25f;
            if (ln < 3) {
                float cdc = (ln == 0) ? cdxm : (ln == 1 ? cdym : cdzm);
                atomicAdd(&out[(long)irm*3 + ln], cdc * s);
            }
        }
    }
    #undef STAGE8
    #undef STAGEW2
}

extern "C" void kernel_launch(void* const* d_in, const int* in_sizes, int n_in,
                              void* d_out, int out_size, void* d_ws, size_t ws_size,
                              hipStream_t stream) {
    const float* h     = (const float*)d_in[0];
    const float* pos   = (const float*)d_in[1];
    const float* ea    = (const float*)d_in[2];
    const float* dist  = (const float*)d_in[3];
    const float* temb  = (const float*)d_in[4];
    const float* adj   = (const float*)d_in[5];
    const float* Wt    = (const float*)d_in[6];
    const float* bt    = (const float*)d_in[7];
    const float* Win   = (const float*)d_in[8];
    const float* bin   = (const float*)d_in[9];
    const float* W1    = (const float*)d_in[10];
    const float* b1    = (const float*)d_in[11];
    const float* W2    = (const float*)d_in[12];
    const float* cs    = (const float*)d_in[13];
    const int*   ei    = (const int*)d_in[14];
    float*       out   = (float*)d_out;
    short*       ws    = (short*)d_ws;

    const size_t WF_SHORTS = 196 * 512;                  // 100352
    const size_t HP_SHORTS = (size_t)N_NODES * 256;      // 25.6M (Hpre bf16)
    const size_t HB_SHORTS = (size_t)N_NODES * 128;      // 12.8M (fallback hbf)
    const bool factored = ws_size >= (WF_SHORTS + HP_SHORTS) * sizeof(short);

    hipMemcpyAsync(out, pos, (size_t)out_size * sizeof(float),
                   hipMemcpyDeviceToDevice, stream);

    if (factored) {
        short* hp = ws + WF_SHORTS;
        pack_weights_f<<<(196*512 + 255) / 256, 256, 0, stream>>>(Wt, Win, W1, W2, ws);
        hpre_kernel<<<(N_NODES + 63) / 64, 256, 0, stream>>>(h, ws, hp);
        edge_kernel_f<<<E_EDGES / 64, 256, 0, stream>>>(
            pos, ea, dist, temb, adj, bt, bin, b1, cs, ei, ws,
            (const unsigned short*)hp, out);
    } else {
        const bool use_hbf = ws_size >= (WF_SHORTS + HB_SHORTS) * sizeof(short);
        short* hbf = ws + WF_SHORTS;
        pack_weights_fb<<<(196*512 + 255) / 256, 256, 0, stream>>>(Wt, Win, W1, W2, ws);
        if (use_hbf) {
            h_pack_kernel<<<(int)(HB_SHORTS / 8 / 256), 256, 0, stream>>>(h, hbf);
            edge_kernel_fb<true><<<E_EDGES / 64, 256, 0, stream>>>(
                h, hbf, pos, ea, dist, temb, adj, bt, bin, b1, cs, ei, ws, out);
        } else {
            edge_kernel_fb<false><<<E_EDGES / 64, 256, 0, stream>>>(
                h, hbf, pos, ea, dist, temb, adj, bt, bin, b1, cs, ei, ws, out);
        }
    }
}

// Round 21
// 506.829 us; speedup vs baseline: 1.0755x; 1.0074x over previous
//
#include <hip/hip_runtime.h>
#include <hip/hip_bf16.h>

#define E_EDGES 1000000
#define N_NODES 100000

typedef __attribute__((ext_vector_type(8))) short bf16x8;
typedef __attribute__((ext_vector_type(4))) float f32x4;

#define WAITV(N) asm volatile("s_waitcnt vmcnt(" #N ")" ::: "memory")
#define WAITL()  asm volatile("s_waitcnt lgkmcnt(0)" ::: "memory")
#define BAR()    __builtin_amdgcn_s_barrier()
#define PRIO1()  __builtin_amdgcn_s_setprio(1)
#define PRIO0()  __builtin_amdgcn_s_setprio(0)

__device__ __forceinline__ short f2bf(float f) {
    union { __bf16 b; short s; } u;
    u.b = (__bf16)f;
    return u.s;
}
__device__ __forceinline__ bf16x8 pack8(float4 a, float4 b) {
    bf16x8 r;
    r[0]=f2bf(a.x); r[1]=f2bf(a.y); r[2]=f2bf(a.z); r[3]=f2bf(a.w);
    r[4]=f2bf(b.x); r[5]=f2bf(b.y); r[6]=f2bf(b.z); r[7]=f2bf(b.w);
    return r;
}
__device__ __forceinline__ float4 ld4(const float* p) {
    return *reinterpret_cast<const float4*>(p);
}
__device__ __forceinline__ float silu1(float x) { return x / (1.f + __expf(-x)); }
__device__ __forceinline__ float tanh1(float x) {
    float e = __expf(2.f * x);
    return 1.f - 2.f / (e + 1.f);
}
__device__ __forceinline__ float bf2f(unsigned short u) {
    return __uint_as_float(((unsigned)u) << 16);
}

__device__ __forceinline__ void stage_frag(const short* gsrc, short* ldst) {
    __builtin_amdgcn_global_load_lds(
        (const __attribute__((address_space(1))) void*)gsrc,
        (__attribute__((address_space(3))) void*)ldst, 16, 0, 0);
}

// swizzled transpose index (shorts) within a per-wave 16x64 slice
__device__ __forceinline__ int tswz(int row, int colS) {
    return (row * 64 + colS) ^ ((row & 7) << 3);
}

// ============ FACTORED PATH ====================================================
// pack layout: frags 0-31 X (Win rows 256..383, ks*8+nt), 32-95 W_time,
// 96-127 W1, 128-131 W2, 132-195 hpre weights.
// Hpre is stored GATHER-ORDERED: position of col c (within each 128-half) is
// (c&15)*8 + (c>>4), so an edge lane reads its 8 needed values as ONE 16B load.
// This kernel ALSO performs the out = pos copy (grid-stride), replacing the
// separate hipMemcpyAsync launch (same-stream ordering protects the atomics).
__global__ void pack_weights_f(const float* __restrict__ Wt,
                               const float* __restrict__ Win,
                               const float* __restrict__ W1,
                               const float* __restrict__ W2,
                               const float* __restrict__ pos,
                               float* __restrict__ out,
                               short* __restrict__ ws)
{
    int gid = blockIdx.x * 256 + threadIdx.x;
    // pos -> out copy: 300000 floats over 100352 threads (3 each, grid-stride)
    for (int i = gid; i < N_NODES * 3; i += 196 * 512)
        out[i] = pos[i];
    if (gid >= 196 * 512) return;
    int frag = gid >> 9, within = gid & 511;
    int l = within >> 3, j = within & 7;
    int lg = l >> 4, ln = l & 15;
    int krow = (lg << 3) + j;
    float v;
    if (frag < 32) {                         // X: Win rows 256..383
        int ks = frag >> 3, nt = frag & 7;
        v = Win[(256 + ks * 32 + krow) * 128 + nt * 16 + ln];
    } else if (frag < 96) {                  // W_time
        int t = frag - 32, ch = t >> 3, sub = t & 7;
        int jj = sub >> 2, ks = sub & 3;
        int jcol = (ch < 4) ? (8 + 2 * ch + jj) : (2 * (ch - 4) + jj);
        v = Wt[(ks * 32 + krow) * 256 + jcol * 16 + ln];
    } else if (frag < 128) {                 // W1
        int t = frag - 96, ch = t >> 3, sub = t & 7;
        int nt = 2 * ch + (sub >> 2), ks = sub & 3;
        v = W1[(ks * 32 + krow) * 128 + nt * 16 + ln];
    } else if (frag < 132) {                 // W2 padded
        int ks = frag - 128;
        v = (ln < 4) ? W2[(ks * 32 + krow) * 4 + ln] : 0.0f;
    } else {                                 // hpre weights: Win rows 0..255
        int q = frag - 132;
        int ntc = q >> 2, ks = q & 3;
        int base = (ntc < 8) ? 0 : 128;
        v = Win[(base + ks * 32 + krow) * 128 + (ntc & 7) * 16 + ln];
    }
    ws[gid] = f2bf(v);
}

// Hpre[n] = h[n] @ Win[0:256], stored gather-ordered (see above).
__global__ __launch_bounds__(256)
void hpre_kernel(const float* __restrict__ h, const short* __restrict__ ws,
                 short* __restrict__ hp)
{
    const int tid = threadIdx.x;
    const int w   = tid >> 6;
    const int l   = tid & 63;
    const int ln  = l & 15;
    const int lg  = l >> 4;
    const int kb  = lg << 3;
    const int nb  = blockIdx.x * 64 + w * 16;
    const int nm  = min(nb + ln, N_NODES - 1);

    bf16x8 af[4];
    #pragma unroll
    for (int ks = 0; ks < 4; ++ks)
        af[ks] = pack8(ld4(h + (long)nm * 128 + ks*32 + kb),
                       ld4(h + (long)nm * 128 + ks*32 + kb + 4));
    const short* wsp = ws + 132 * 512;
    #pragma unroll
    for (int ntc = 0; ntc < 16; ++ntc) {
        f32x4 acc = (f32x4){0.f,0.f,0.f,0.f};
        #pragma unroll
        for (int ks = 0; ks < 4; ++ks) {
            bf16x8 b = *reinterpret_cast<const bf16x8*>(&wsp[(ntc*4+ks)*512 + l*8]);
            acc = __builtin_amdgcn_mfma_f32_16x16x32_bf16(af[ks], b, acc, 0, 0, 0);
        }
        // gather-ordered store: col c = ntc*16 + ln -> half*128 + ln*8 + (ntc&7)
        const int off = ((ntc < 8) ? 0 : 128) + ln * 8 + (ntc & 7);
        #pragma unroll
        for (int r = 0; r < 4; ++r) {
            int node = nb + (lg<<2) + r;
            if (node < N_NODES)
                hp[(long)node * 256 + off] = f2bf(acc[r]);
        }
    }
}

// factored edge kernel: 8 BIG phases (16 KB chunks, depth-2 dbuf) + W2.
// R20 schedule (64 VGPR, prologue gathers) + setprio around MFMA clusters.
__global__ __launch_bounds__(256, 3)
void edge_kernel_f(const float* __restrict__ pos,
                   const float* __restrict__ ea,
                   const float* __restrict__ dst_f,
                   const float* __restrict__ temb,
                   const float* __restrict__ adj,
                   const float* __restrict__ btime,
                   const float* __restrict__ bin,
                   const float* __restrict__ b1,
                   const float* __restrict__ cscale,
                   const int*   __restrict__ ei,
                   const short* __restrict__ ws,
                   const unsigned short* __restrict__ hp,
                   float* __restrict__ out)
{
    __shared__ __align__(16) short Wb[2][8192];   // 2 x 16 KB big-chunk dbuf
    __shared__ float sBias[512];

    const int tid = threadIdx.x;
    const int w   = tid >> 6;
    const int l   = tid & 63;
    const int ln  = l & 15;
    const int lg  = l >> 4;
    const int kb  = lg << 3;
    const int e0w = blockIdx.x * 64 + w * 16;
    const int em  = e0w + ln;

    const int ir = ei[em];
    const int ic = ei[E_EDGES + em];

    #pragma unroll
    for (int i = 0; i < 2; ++i) {
        int idx = tid + i * 256;
        float v = (idx < 128) ? bin[idx] : (idx < 256) ? b1[idx - 128] : btime[idx - 256];
        sBias[idx] = v;
    }
    WAITL();

    // big chunk C (16 frags): wave w stages frags 4w..4w+3 (its own 4 KB slice)
    #define STAGE16(C) { \
        const short* g_ = ws + (C) * 8192 + (w*4) * 512 + l * 8; \
        short* d_ = &Wb[(C) & 1][(w*4) * 512]; \
        stage_frag(g_, d_); \
        stage_frag(g_ + 512, d_ + 512); \
        stage_frag(g_ + 1024, d_ + 1024); \
        stage_frag(g_ + 1536, d_ + 1536); }
    #define STAGEW2() { \
        stage_frag(ws + 128 * 512 + w * 512 + l * 8, &Wb[0][w * 512]); }

    // C-layout row -> edge indices via shfl
    int irg[4], icg[4];
    #pragma unroll
    for (int r = 0; r < 4; ++r) {
        irg[r] = __shfl(ir, (lg<<2) + r);
        icg[r] = __shfl(ic, (lg<<2) + r);
    }

    // ---- prologue: 8 vectorized Hpre gathers + ea|dist f32 loads + C0,C1 ----
    bf16x8 gaV[4], gbV[4];                    // gather-ordered: one 16B load each
    #pragma unroll
    for (int r = 0; r < 4; ++r) {
        gaV[r] = *reinterpret_cast<const bf16x8*>(hp + (long)irg[r]*256 + ln*8);
        gbV[r] = *reinterpret_cast<const bf16x8*>(hp + (long)icg[r]*256 + 128 + ln*8);
    }
    float4 tf[8];
    #pragma unroll
    for (int k2 = 0; k2 < 4; ++k2) {
        const float* q = (k2 < 2) ? (ea    + (long)em*64 + k2*32 + kb)
                                  : (dst_f + (long)em*64 + (k2-2)*32 + kb);
        tf[2*k2]   = ld4(q);
        tf[2*k2+1] = ld4(q + 4);
    }
    STAGE16(0);
    STAGE16(1);
    WAITV(8);                                 // gathers + tf retired; C0,C1 in flight

    f32x4 accX[8];
    #pragma unroll
    for (int r = 0; r < 4; ++r)
        #pragma unroll
        for (int nt = 0; nt < 8; ++nt)
            accX[nt][r] = bf2f((unsigned short)gaV[r][nt]) + bf2f((unsigned short)gbV[r][nt]);
    bf16x8 af_a[4];
    #pragma unroll
    for (int k2 = 0; k2 < 4; ++k2) af_a[k2] = pack8(tf[2*k2], tf[2*k2+1]);

    // ---- phase 0: C0 = X ks0,ks1 (no stage issue; dbuf full) ----
    WAITV(4);                                 // C0 done; C1 in flight
    BAR();
    {
        const short* wb = &Wb[0][0];
        PRIO1();
        #pragma unroll
        for (int ksl = 0; ksl < 2; ++ksl)
            #pragma unroll
            for (int nt = 0; nt < 8; ++nt) {
                bf16x8 b = *reinterpret_cast<const bf16x8*>(&wb[(ksl*8+nt)*512 + l*8]);
                accX[nt] = __builtin_amdgcn_mfma_f32_16x16x32_bf16(af_a[ksl], b, accX[nt], 0, 0, 0);
            }
        PRIO0();
    }

    // ---- phase 1: C1 = X ks2,ks3 ; issue temb then STAGE(C2); LN; ttf ----
    WAITV(0);
    BAR();
    #pragma unroll
    for (int k2 = 0; k2 < 4; ++k2) {         // temb loads (older than stage C2)
        tf[2*k2]   = ld4(temb + (long)em * 128 + k2*32 + kb);
        tf[2*k2+1] = ld4(temb + (long)em * 128 + k2*32 + kb + 4);
    }
    STAGE16(2);
    {
        const short* wb = &Wb[1][0];
        PRIO1();
        #pragma unroll
        for (int ksl = 0; ksl < 2; ++ksl)
            #pragma unroll
            for (int nt = 0; nt < 8; ++nt) {
                bf16x8 b = *reinterpret_cast<const bf16x8*>(&wb[(ksl*8+nt)*512 + l*8]);
                accX[nt] = __builtin_amdgcn_mfma_f32_16x16x32_bf16(af_a[2+ksl], b, accX[nt], 0, 0, 0);
            }
        PRIO0();
    }
    // bias + LayerNorm (register/LDS only)
    #pragma unroll
    for (int nt = 0; nt < 8; ++nt) {
        float bv = sBias[(nt<<4) + ln];
        #pragma unroll
        for (int r = 0; r < 4; ++r) accX[nt][r] += bv;
    }
    #pragma unroll
    for (int r = 0; r < 4; ++r) {
        float p = 0.f, q = 0.f;
        #pragma unroll
        for (int nt = 0; nt < 8; ++nt) { float x = accX[nt][r]; p += x; q += x*x; }
        #pragma unroll
        for (int d2 = 1; d2 < 16; d2 <<= 1) { p += __shfl_xor(p, d2); q += __shfl_xor(q, d2); }
        float mean = p * 0.0078125f;
        float var  = q * 0.0078125f - mean * mean;
        float rstd = rsqrtf(var + 1e-6f);
        #pragma unroll
        for (int nt = 0; nt < 8; ++nt)
            accX[nt][r] = (accX[nt][r] - mean) * rstd;
    }
    WAITV(4);                                 // temb done; C2's 4 stage ops in flight
    bf16x8 ttf[4];
    #pragma unroll
    for (int k2 = 0; k2 < 4; ++k2) {
        float4 va = tf[2*k2], vb = tf[2*k2+1];
        va.x=silu1(va.x); va.y=silu1(va.y); va.z=silu1(va.z); va.w=silu1(va.w);
        vb.x=silu1(vb.x); vb.y=silu1(vb.y); vb.z=silu1(vb.z); vb.w=silu1(vb.w);
        ttf[k2] = pack8(va, vb);
    }

    // ---- phases 2..5: T big chunks C2..C5 (2 t-values each), FiLM inline ----
    #pragma unroll
    for (int tc = 0; tc < 4; ++tc) {
        WAITV(0);
        BAR();
        STAGE16(3 + tc);                      // C3..C6
        const short* wb = &Wb[tc & 1][0];     // (2+tc)&1 == tc&1
        #pragma unroll
        for (int tl = 0; tl < 2; ++tl) {
            const int t = 2*tc + tl;
            #pragma unroll
            for (int jj = 0; jj < 2; ++jj) {
                f32x4 tt = (f32x4){0.f,0.f,0.f,0.f};
                PRIO1();
                #pragma unroll
                for (int ks = 0; ks < 4; ++ks) {
                    bf16x8 b = *reinterpret_cast<const bf16x8*>(&wb[(tl*8 + jj*4 + ks)*512 + l*8]);
                    tt = __builtin_amdgcn_mfma_f32_16x16x32_bf16(ttf[ks], b, tt, 0, 0, 0);
                }
                PRIO0();
                if (t < 4) {
                    const int jx = 2*t + jj;
                    float bsc = sBias[384 + (jx<<4) + ln];
                    #pragma unroll
                    for (int r = 0; r < 4; ++r) accX[jx][r] *= (1.f + tt[r] + bsc);
                } else {
                    const int jx = 2*(t-4) + jj;
                    float bsh = sBias[256 + (jx<<4) + ln];
                    #pragma unroll
                    for (int r = 0; r < 4; ++r) accX[jx][r] += tt[r] + bsh;
                }
            }
        }
    }

    // ---- transpose inv -> A-layout in own slice of Wb[1] (C5 consumed; C7
    //      will overwrite this exact slice only after phase-6's barrier) ----
    short* tbW = &Wb[1][w * 2048];
    bf16x8 iaf[4];
    WAITL();                                  // own ds_reads of C5 retired
    BAR();                                    // all waves done with C5
    #pragma unroll
    for (int hpx = 0; hpx < 2; ++hpx) {
        #pragma unroll
        for (int nt4 = 0; nt4 < 4; ++nt4) {
            const int nt = hpx*4 + nt4;
            #pragma unroll
            for (int r = 0; r < 4; ++r)
                tbW[tswz((lg<<2) + r, (nt4<<4) + ln)] = f2bf(accX[nt][r]);
        }
        #pragma unroll
        for (int k2 = 0; k2 < 2; ++k2)
            iaf[hpx*2 + k2] = *reinterpret_cast<const bf16x8*>(&tbW[tswz(ln, (k2<<5) + kb)]);
    }
    WAITL();                                  // transpose reads done before stage(C7)

    // ---- phase 6: C6 = W1 u0,u1 ----
    f32x4 accY[8];
    #pragma unroll
    for (int i = 0; i < 8; ++i) accY[i] = (f32x4){0.f,0.f,0.f,0.f};
    WAITV(0);
    BAR();
    STAGE16(7);
    {
        const short* wb = &Wb[0][0];
        PRIO1();
        #pragma unroll
        for (int ul = 0; ul < 2; ++ul)
            #pragma unroll
            for (int s = 0; s < 2; ++s) {
                const int nt = 2*ul + s;
                #pragma unroll
                for (int ks = 0; ks < 4; ++ks) {
                    bf16x8 b = *reinterpret_cast<const bf16x8*>(&wb[(ul*8 + s*4 + ks)*512 + l*8]);
                    accY[nt] = __builtin_amdgcn_mfma_f32_16x16x32_bf16(iaf[ks], b, accY[nt], 0, 0, 0);
                }
            }
        PRIO0();
    }

    // ---- phase 7: C7 = W1 u2,u3 ; stage W2 ----
    WAITV(0);
    BAR();
    STAGEW2();                                // 4 frags -> Wb[0]
    {
        const short* wb = &Wb[1][0];
        PRIO1();
        #pragma unroll
        for (int ul = 0; ul < 2; ++ul)
            #pragma unroll
            for (int s = 0; s < 2; ++s) {
                const int nt = 4 + 2*ul + s;
                #pragma unroll
                for (int ks = 0; ks < 4; ++ks) {
                    bf16x8 b = *reinterpret_cast<const bf16x8*>(&wb[(ul*8 + s*4 + ks)*512 + l*8]);
                    accY[nt] = __builtin_amdgcn_mfma_f32_16x16x32_bf16(iaf[ks], b, accY[nt], 0, 0, 0);
                }
            }
        PRIO0();
    }

    // ---- silu + transpose back in own slice of Wb[1] (C7 consumed) ----
    bf16x8 yaf[4];
    WAITL();
    BAR();
    #pragma unroll
    for (int hpx = 0; hpx < 2; ++hpx) {
        #pragma unroll
        for (int nt4 = 0; nt4 < 4; ++nt4) {
            const int nt = hpx*4 + nt4;
            float bv = sBias[128 + (nt<<4) + ln];
            #pragma unroll
            for (int r = 0; r < 4; ++r)
                tbW[tswz((lg<<2) + r, (nt4<<4) + ln)] = f2bf(silu1(accY[nt][r] + bv));
        }
        #pragma unroll
        for (int k2 = 0; k2 < 2; ++k2)
            yaf[hpx*2 + k2] = *reinterpret_cast<const bf16x8*>(&tbW[tswz(ln, (k2<<5) + kb)]);
    }

    // ---- W2 stage (Wb[0]) ----
    WAITV(0);
    BAR();
    f32x4 accZ = (f32x4){0.f,0.f,0.f,0.f};
    {
        const short* wb = &Wb[0][0];
        PRIO1();
        #pragma unroll
        for (int ks = 0; ks < 4; ++ks) {
            bf16x8 b = *reinterpret_cast<const bf16x8*>(&wb[ks*512 + l*8]);
            accZ = __builtin_amdgcn_mfma_f32_16x16x32_bf16(yaf[ks], b, accZ, 0, 0, 0);
        }
        PRIO0();
    }

    // ---- epilogue ----
    {
        float dx = pos[ir*3+0] - pos[ic*3+0];
        float dy = pos[ir*3+1] - pos[ic*3+1];
        float dz = pos[ir*3+2] - pos[ic*3+2];
        float a0 = adj[em*3+0], a1 = adj[em*3+1], a2 = adj[em*3+2];
        float nrm = sqrtf(dx*dx + dy*dy + dz*dz);
        float sc  = cscale[0] / fmaxf(nrm, 1e-8f);
        float cdx = dx * sc, cdy = dy * sc, cdz = dz * sc;
        #pragma unroll
        for (int r = 0; r < 4; ++r) {
            const int m = (lg<<2) + r;
            float z  = tanh1(accZ[r]);
            float w0 = __shfl(a0, m), w1 = __shfl(a1, m), w2 = __shfl(a2, m);
            int   irm  = __shfl(ir, m);
            float cdxm = __shfl(cdx, m), cdym = __shfl(cdy, m), cdzm = __shfl(cdz, m);
            float wt = (ln == 0) ? 1.0f : (ln == 1 ? w0 : (ln == 2 ? w1 : (ln == 3 ? w2 : 0.0f)));
            float v = z * wt;
            v += __shfl_xor(v, 1);
            v += __shfl_xor(v, 2);
            float s = v * 0.25f;
            if (ln < 3) {
                float cdc = (ln == 0) ? cdxm : (ln == 1 ? cdym : cdzm);
                atomicAdd(&out[(long)irm*3 + ln], cdc * s);
            }
        }
    }
    #undef STAGE16
    #undef STAGEW2
}

// ============ FALLBACK PATH (R14, proven 552 us) ===============================
__global__ void pack_weights_fb(const float* __restrict__ Wt,
                                const float* __restrict__ Win,
                                const float* __restrict__ W1,
                                const float* __restrict__ W2,
                                short* __restrict__ ws)
{
    int gid = blockIdx.x * 256 + threadIdx.x;
    if (gid >= 196 * 512) return;
    int frag = gid >> 9, within = gid & 511;
    int l = within >> 3, j = within & 7;
    int lg = l >> 4, ln = l & 15;
    int krow = (lg << 3) + j;
    float v;
    if (frag < 96) {
        int cs = frag >> 3, nt = frag & 7;
        int seg = cs >> 2, ks = cs & 3;
        int base = (seg == 0) ? 256 : (seg == 1) ? 0 : 128;
        int k = base + ks * 32 + krow;
        v = Win[k * 128 + nt * 16 + ln];
    } else if (frag < 160) {
        int t = frag - 96, ch = t >> 3, sub = t & 7;
        int jj = sub >> 2, ks = sub & 3;
        int jcol = (ch < 4) ? (8 + 2 * ch + jj) : (2 * (ch - 4) + jj);
        int k = ks * 32 + krow;
        v = Wt[k * 256 + jcol * 16 + ln];
    } else if (frag < 192) {
        int t = frag - 160, ch = t >> 3, sub = t & 7;
        int nt = 2 * ch + (sub >> 2), ks = sub & 3;
        int k = ks * 32 + krow;
        v = W1[k * 128 + nt * 16 + ln];
    } else {
        int ks = frag - 192;
        int k = ks * 32 + krow;
        v = (ln < 4) ? W2[k * 4 + ln] : 0.0f;
    }
    ws[gid] = f2bf(v);
}

__global__ void h_pack_kernel(const float* __restrict__ h, short* __restrict__ hbf) {
    long i = (long)(blockIdx.x * 256 + threadIdx.x) * 8;
    if (i >= (long)N_NODES * 128) return;
    float4 a = ld4(h + i), b = ld4(h + i + 4);
    *reinterpret_cast<bf16x8*>(hbf + i) = pack8(a, b);
}

template<bool HBF>
__global__ __launch_bounds__(256, 3)
void edge_kernel_fb(const float* __restrict__ h,
                    const short* __restrict__ hbf,
                    const float* __restrict__ pos,
                    const float* __restrict__ ea,
                    const float* __restrict__ dst_f,
                    const float* __restrict__ temb,
                    const float* __restrict__ adj,
                    const float* __restrict__ btime,
                    const float* __restrict__ bin,
                    const float* __restrict__ b1,
                    const float* __restrict__ cscale,
                    const int*   __restrict__ ei,
                    const short* __restrict__ ws,
                    float* __restrict__ out)
{
    __shared__ __align__(16) short Wb[3][4096];
    __shared__ float sBias[512];

    const int tid = threadIdx.x;
    const int w   = tid >> 6;
    const int l   = tid & 63;
    const int ln  = l & 15;
    const int lg  = l >> 4;
    const int kb  = lg << 3;
    const int e0w = blockIdx.x * 64 + w * 16;
    const int em  = e0w + ln;

    const int ir = ei[em];
    const int ic = ei[E_EDGES + em];

    #pragma unroll
    for (int i = 0; i < 2; ++i) {
        int idx = tid + i * 256;
        float v = (idx < 128) ? bin[idx] : (idx < 256) ? b1[idx - 128] : btime[idx - 256];
        sBias[idx] = v;
    }
    WAITL();

    #define STAGE8(p) { \
        const short* g_ = ws + (p) * 4096 + (w*2) * 512 + l * 8; \
        short* d_ = &Wb[(p) % 3][(w*2) * 512]; \
        stage_frag(g_, d_); \
        stage_frag(g_ + 512, d_ + 512); }
    #define STAGEW2() { \
        stage_frag(ws + 24 * 4096 + w * 512 + l * 8, &Wb[0][w * 512]); }

    float4 tf[8];
    #pragma unroll
    for (int k2 = 0; k2 < 4; ++k2) {
        const float* q = (k2 < 2) ? (ea    + (long)em*64 + k2*32 + kb)
                                  : (dst_f + (long)em*64 + (k2-2)*32 + kb);
        tf[2*k2]   = ld4(q);
        tf[2*k2+1] = ld4(q + 4);
    }
    bf16x8 af_b[4];
    if (HBF) {
        #pragma unroll
        for (int k2 = 0; k2 < 4; ++k2)
            af_b[k2] = *reinterpret_cast<const bf16x8*>(hbf + (long)ir * 128 + k2*32 + kb);
    } else {
        #pragma unroll
        for (int k2 = 0; k2 < 4; ++k2)
            af_b[k2] = pack8(ld4(h + (long)ir*128 + k2*32 + kb),
                             ld4(h + (long)ir*128 + k2*32 + kb + 4));
    }
    STAGE8(0);
    STAGE8(1);
    if (HBF) { WAITV(8); } else { WAITV(4); }
    bf16x8 af_a[4];
    #pragma unroll
    for (int k2 = 0; k2 < 4; ++k2) af_a[k2] = pack8(tf[2*k2], tf[2*k2+1]);

    f32x4 accX[8];
    #pragma unroll
    for (int i = 0; i < 8; ++i) accX[i] = (f32x4){0.f,0.f,0.f,0.f};
    bf16x8 af_c[4];

    #pragma unroll
    for (int c = 0; c < 12; ++c) {
        if (HBF) {
            if (c == 4 || c == 5) { WAITV(6); } else { WAITV(2); }
        } else {
            if (c == 4 || c == 5) { WAITV(10); } else { WAITV(2); }
        }
        BAR();
        if (c == 11) {
            #pragma unroll
            for (int k2 = 0; k2 < 4; ++k2) {
                tf[2*k2]   = ld4(temb + (long)em * 128 + k2*32 + kb);
                tf[2*k2+1] = ld4(temb + (long)em * 128 + k2*32 + kb + 4);
            }
        }
        STAGE8(c + 2);
        if (c == 3) {
            if (HBF) {
                #pragma unroll
                for (int k2 = 0; k2 < 4; ++k2)
                    af_c[k2] = *reinterpret_cast<const bf16x8*>(hbf + (long)ic * 128 + k2*32 + kb);
            } else {
                #pragma unroll
                for (int k2 = 0; k2 < 4; ++k2)
                    af_c[k2] = pack8(ld4(h + (long)ic*128 + k2*32 + kb),
                                     ld4(h + (long)ic*128 + k2*32 + kb + 4));
            }
        }
        {
            const int ks = c & 3;
            const bf16x8 a_use = (c < 4) ? af_a[ks] : (c < 8) ? af_b[ks] : af_c[ks];
            const short* wb = &Wb[c % 3][0];
            #pragma unroll
            for (int nt = 0; nt < 8; ++nt) {
                bf16x8 b = *reinterpret_cast<const bf16x8*>(&wb[nt*512 + l*8]);
                accX[nt] = __builtin_amdgcn_mfma_f32_16x16x32_bf16(a_use, b, accX[nt], 0, 0, 0);
            }
        }
    }

    #pragma unroll
    for (int nt = 0; nt < 8; ++nt) {
        float bv = sBias[(nt<<4) + ln];
        #pragma unroll
        for (int r = 0; r < 4; ++r) accX[nt][r] += bv;
    }
    #pragma unroll
    for (int r = 0; r < 4; ++r) {
        float p = 0.f, q = 0.f;
        #pragma unroll
        for (int nt = 0; nt < 8; ++nt) { float x = accX[nt][r]; p += x; q += x*x; }
        #pragma unroll
        for (int d2 = 1; d2 < 16; d2 <<= 1) { p += __shfl_xor(p, d2); q += __shfl_xor(q, d2); }
        float mean = p * 0.0078125f;
        float var  = q * 0.0078125f - mean * mean;
        float rstd = rsqrtf(var + 1e-6f);
        #pragma unroll
        for (int nt = 0; nt < 8; ++nt)
            accX[nt][r] = (accX[nt][r] - mean) * rstd;
    }

    WAITV(2);
    bf16x8 ttf[4];
    #pragma unroll
    for (int k2 = 0; k2 < 4; ++k2) {
        float4 va = tf[2*k2], vb = tf[2*k2+1];
        va.x=silu1(va.x); va.y=silu1(va.y); va.z=silu1(va.z); va.w=silu1(va.w);
        vb.x=silu1(vb.x); vb.y=silu1(vb.y); vb.z=silu1(vb.z); vb.w=silu1(vb.w);
        ttf[k2] = pack8(va, vb);
    }

    #pragma unroll
    for (int t = 0; t < 8; ++t) {
        WAITV(2);
        BAR();
        STAGE8(14 + t);
        {
            const short* wb = &Wb[(12 + t) % 3][0];
            #pragma unroll
            for (int jj = 0; jj < 2; ++jj) {
                f32x4 tt = (f32x4){0.f,0.f,0.f,0.f};
                #pragma unroll
                for (int ks = 0; ks < 4; ++ks) {
                    bf16x8 b = *reinterpret_cast<const bf16x8*>(&wb[(jj*4+ks)*512 + l*8]);
                    tt = __builtin_amdgcn_mfma_f32_16x16x32_bf16(ttf[ks], b, tt, 0, 0, 0);
                }
                if (t < 4) {
                    const int jx = 2*t + jj;
                    float bsc = sBias[384 + (jx<<4) + ln];
                    #pragma unroll
                    for (int r = 0; r < 4; ++r) accX[jx][r] *= (1.f + tt[r] + bsc);
                } else {
                    const int jx = 2*(t-4) + jj;
                    float bsh = sBias[256 + (jx<<4) + ln];
                    #pragma unroll
                    for (int r = 0; r < 4; ++r) accX[jx][r] += tt[r] + bsh;
                }
            }
        }
    }

    short* tbW = &Wb[1][w * 1024];
    bf16x8 iaf[4];
    WAITL();
    BAR();
    #pragma unroll
    for (int hpx = 0; hpx < 2; ++hpx) {
        #pragma unroll
        for (int nt4 = 0; nt4 < 4; ++nt4) {
            const int nt = hpx*4 + nt4;
            #pragma unroll
            for (int r = 0; r < 4; ++r)
                tbW[tswz((lg<<2) + r, (nt4<<4) + ln)] = f2bf(accX[nt][r]);
        }
        #pragma unroll
        for (int k2 = 0; k2 < 2; ++k2)
            iaf[hpx*2 + k2] = *reinterpret_cast<const bf16x8*>(&tbW[tswz(ln, (k2<<5) + kb)]);
    }
    WAITL();

    f32x4 accY[8];
    #pragma unroll
    for (int i = 0; i < 8; ++i) accY[i] = (f32x4){0.f,0.f,0.f,0.f};
    #pragma unroll
    for (int u = 0; u < 4; ++u) {
        if (u < 3) { WAITV(2); } else { WAITV(1); }
        BAR();
        if (u < 2)       { STAGE8(22 + u); }
        else if (u == 2) { STAGEW2(); }
        {
            const short* wb = &Wb[(20 + u) % 3][0];
            #pragma unroll
            for (int s = 0; s < 2; ++s) {
                const int nt = 2*u + s;
                #pragma unroll
                for (int ks = 0; ks < 4; ++ks) {
                    bf16x8 b = *reinterpret_cast<const bf16x8*>(&wb[(s*4+ks)*512 + l*8]);
                    accY[nt] = __builtin_amdgcn_mfma_f32_16x16x32_bf16(iaf[ks], b, accY[nt], 0, 0, 0);
                }
            }
        }
    }

    bf16x8 yaf[4];
    WAITL();
    BAR();
    #pragma unroll
    for (int hpx = 0; hpx < 2; ++hpx) {
        #pragma unroll
        for (int nt4 = 0; nt4 < 4; ++nt4) {
            const int nt = hpx*4 + nt4;
            float bv = sBias[128 + (nt<<4) + ln];
            #pragma unroll
            for (int r = 0; r < 4; ++r)
                tbW[tswz((lg<<2) + r, (nt4<<4) + ln)] = f2bf(silu1(accY[nt][r] + bv));
        }
        #pragma unroll
        for (int k2 = 0; k2 < 2; ++k2)
            yaf[hpx*2 + k2] = *reinterpret_cast<const bf16x8*>(&tbW[tswz(ln, (k2<<5) + kb)]);
    }

    WAITV(0);
    BAR();
    f32x4 accZ = (f32x4){0.f,0.f,0.f,0.f};
    {
        const short* wb = &Wb[0][0];
        #pragma unroll
        for (int ks = 0; ks < 4; ++ks) {
            bf16x8 b = *reinterpret_cast<const bf16x8*>(&wb[ks*512 + l*8]);
            accZ = __builtin_amdgcn_mfma_f32_16x16x32_bf16(yaf[ks], b, accZ, 0, 0, 0);
        }
    }

    {
        float dx = pos[ir*3+0] - pos[ic*3+0];
        float dy = pos[ir*3+1] - pos[ic*3+1];
        float dz = pos[ir*3+2] - pos[ic*3+2];
        float a0 = adj[em*3+0], a1 = adj[em*3+1], a2 = adj[em*3+2];
        float nrm = sqrtf(dx*dx + dy*dy + dz*dz);
        float sc  = cscale[0] / fmaxf(nrm, 1e-8f);
        float cdx = dx * sc, cdy = dy * sc, cdz = dz * sc;
        #pragma unroll
        for (int r = 0; r < 4; ++r) {
            const int m = (lg<<2) + r;
            float z  = tanh1(accZ[r]);
            float w0 = __shfl(a0, m), w1 = __shfl(a1, m), w2 = __shfl(a2, m);
            int   irm  = __shfl(ir, m);
            float cdxm = __shfl(cdx, m), cdym = __shfl(cdy, m), cdzm = __shfl(cdz, m);
            float wt = (ln == 0) ? 1.0f : (ln == 1 ? w0 : (ln == 2 ? w1 : (ln == 3 ? w2 : 0.0f)));
            float v = z * wt;
            v += __shfl_xor(v, 1);
            v += __shfl_xor(v, 2);
            float s = v * 0.25f;
            if (ln < 3) {
                float cdc = (ln == 0) ? cdxm : (ln == 1 ? cdym : cdzm);
                atomicAdd(&out[(long)irm*3 + ln], cdc * s);
            }
        }
    }
    #undef STAGE8
    #undef STAGEW2
}

extern "C" void kernel_launch(void* const* d_in, const int* in_sizes, int n_in,
                              void* d_out, int out_size, void* d_ws, size_t ws_size,
                              hipStream_t stream) {
    const float* h     = (const float*)d_in[0];
    const float* pos   = (const float*)d_in[1];
    const float* ea    = (const float*)d_in[2];
    const float* dist  = (const float*)d_in[3];
    const float* temb  = (const float*)d_in[4];
    const float* adj   = (const float*)d_in[5];
    const float* Wt    = (const float*)d_in[6];
    const float* bt    = (const float*)d_in[7];
    const float* Win   = (const float*)d_in[8];
    const float* bin   = (const float*)d_in[9];
    const float* W1    = (const float*)d_in[10];
    const float* b1    = (const float*)d_in[11];
    const float* W2    = (const float*)d_in[12];
    const float* cs    = (const float*)d_in[13];
    const int*   ei    = (const int*)d_in[14];
    float*       out   = (float*)d_out;
    short*       ws    = (short*)d_ws;

    const size_t WF_SHORTS = 196 * 512;                  // 100352
    const size_t HP_SHORTS = (size_t)N_NODES * 256;      // 25.6M (Hpre bf16)
    const size_t HB_SHORTS = (size_t)N_NODES * 128;      // 12.8M (fallback hbf)
    const bool factored = ws_size >= (WF_SHORTS + HP_SHORTS) * sizeof(short);

    if (factored) {
        short* hp = ws + WF_SHORTS;
        // pack kernel also performs out = pos (grid-stride), saving one launch
        pack_weights_f<<<(196*512 + 255) / 256, 256, 0, stream>>>(Wt, Win, W1, W2,
                                                                  pos, out, ws);
        hpre_kernel<<<(N_NODES + 63) / 64, 256, 0, stream>>>(h, ws, hp);
        edge_kernel_f<<<E_EDGES / 64, 256, 0, stream>>>(
            pos, ea, dist, temb, adj, bt, bin, b1, cs, ei, ws,
            (const unsigned short*)hp, out);
    } else {
        const bool use_hbf = ws_size >= (WF_SHORTS + HB_SHORTS) * sizeof(short);
        short* hbf = ws + WF_SHORTS;
        hipMemcpyAsync(out, pos, (size_t)out_size * sizeof(float),
                       hipMemcpyDeviceToDevice, stream);
        pack_weights_fb<<<(196*512 + 255) / 256, 256, 0, stream>>>(Wt, Win, W1, W2, ws);
        if (use_hbf) {
            h_pack_kernel<<<(int)(HB_SHORTS / 8 / 256), 256, 0, stream>>>(h, hbf);
            edge_kernel_fb<true><<<E_EDGES / 64, 256, 0, stream>>>(
                h, hbf, pos, ea, dist, temb, adj, bt, bin, b1, cs, ei, ws, out);
        } else {
            edge_kernel_fb<false><<<E_EDGES / 64, 256, 0, stream>>>(
                h, hbf, pos, ea, dist, temb, adj, bt, bin, b1, cs, ei, ws, out);
        }
    }
}